// Round 11
// baseline (735.701 us; speedup 1.0000x reference)
//
#include <hip/hip_runtime.h>
#include <hip/hip_bf16.h>

#define HDIM 96
#define TILE 128
#define NTILE 64

typedef __attribute__((ext_vector_type(8))) short  short8;
typedef __attribute__((ext_vector_type(4))) short  short4v;
typedef __attribute__((ext_vector_type(4))) float  float4v;
typedef __attribute__((ext_vector_type(2))) float  float2v;
typedef __attribute__((ext_vector_type(4))) unsigned int uint4v;
typedef __attribute__((ext_vector_type(2))) unsigned int uint2v;

// fast bf16 round (round-half-away): 2 VALU inst vs ~5 for full RNE.
static __device__ __forceinline__ short f2bf(float f){
    unsigned u = __float_as_uint(f);
    return (short)((u + 0x8000u) >> 16);
}
static __device__ __forceinline__ float bf2f(short s){
    unsigned u = ((unsigned)(unsigned short)s) << 16;
    return __uint_as_float(u);
}
// fast silu: v * rcp(1+exp(-v)) — v_rcp_f32 is ~1ulp, fine at bf16 tolerance
static __device__ __forceinline__ float silu_f(float v){
    return v * __builtin_amdgcn_rcpf(1.0f + __expf(-v));
}
// packed-pair silu -> packed bf16 u32 (elem0 low 16, elem1 high 16); v_pk_* friendly.
static __device__ __forceinline__ unsigned silu2_pack(float2v v){
    float e0 = __expf(-v[0]);
    float e1 = __expf(-v[1]);
    float2v ep = {e0, e1};
    const float2v one2 = {1.0f, 1.0f};
    ep += one2;
    float2v q = { __builtin_amdgcn_rcpf(ep[0]), __builtin_amdgcn_rcpf(ep[1]) };
    float2v res = v * q;
    unsigned pa = __float_as_uint(res[0]) + 0x8000u;
    unsigned pb = __float_as_uint(res[1]) + 0x8000u;
    return __builtin_amdgcn_perm(pb, pa, 0x07060302);
}

// async global->LDS, 16B per lane, per-lane GLOBAL src, wave-uniform LDS base (+lane*16 in HW)
typedef __attribute__((address_space(1))) const unsigned int guint;
typedef __attribute__((address_space(3))) unsigned int luint;
static __device__ __forceinline__ void gload_lds16(const void* g, void* l){
    __builtin_amdgcn_global_load_lds((guint*)g, (luint*)l, 16, 0, 0);
}

// ---------------- weight swizzle + workspace zeroing + edge histogram (merged) ----------------
// hist phase is safe here because deg is zeroed by a hipMemsetAsync that PRECEDES
// this kernel in stream order.
struct SwJob { const float* src; int ck; int ks; int ksrc; };
struct SwTable { SwJob j[22]; };

__global__ __launch_bounds__(256) void swizzle_all(SwTable T, const float* __restrict__ msg_w1,
                                                   short* __restrict__ dst, short* __restrict__ dst2,
                                                   int total1, int total2,
                                                   float* __restrict__ aggrZ, float* __restrict__ pooledZ,
                                                   int nA, int nP,
                                                   const int* __restrict__ recH, int* __restrict__ deg, int E){
    int gid = blockIdx.x*256 + threadIdx.x;
    if (gid < total1) {
        int ksg = gid / 3072;
        int e   = gid % 3072;
        const float* src = T.j[0].src; int k0 = 0, ksrc = 0;
        #pragma unroll
        for (int jj = 0; jj < 22; ++jj){
            int s = T.j[jj].ck;
            if (ksg >= s && ksg < s + T.j[jj].ks){ src = T.j[jj].src; k0 = (ksg - s)*32; ksrc = T.j[jj].ksrc; }
        }
        int nt   = e >> 9;
        int rem  = e & 511;
        int lane = rem >> 3;
        int jx   = rem & 7;
        int k = k0 + ((lane >> 4) << 3) + jx;
        int f = nt*16 + (lane & 15);
        float v = (k < ksrc) ? src[(size_t)k*HDIM + f] : 0.0f;
        dst[gid] = f2bf(v);
    } else if (gid < total1 + total2) {
        int g2 = gid - total1;
        int layer = g2 / 18432;
        int e     = g2 % 18432;
        int ksg = e / 6144;
        int rem = e % 6144;
        int nt   = rem >> 9;
        int r2   = rem & 511;
        int lane = r2 >> 3;
        int jx   = r2 & 7;
        int k = ksg*32 + ((lane >> 4) << 3) + jx;     // 0..95
        int f = nt*16 + (lane & 15);                  // 0..191
        int row = (f < 96) ? k : (96 + k);
        int col = (f < 96) ? f : (f - 96);
        dst2[g2] = f2bf(msg_w1[(size_t)layer*193*96 + (size_t)row*96 + col]);
    } else if (gid < total1 + total2 + nA + nP) {
        int gz = gid - total1 - total2;
        const float4v z = {0.f,0.f,0.f,0.f};
        if (gz < nA)  ((float4v*)aggrZ)[gz] = z;
        else          ((float4v*)pooledZ)[gz - nA] = z;
    } else {
        int e = gid - total1 - total2 - nA - nP;
        if (e < E) atomicAdd(&deg[recH[e]], 1);
    }
}

// ---------------- edge sorting scans (counting sort by rec) ----------------
__global__ __launch_bounds__(256) void scan_part(const int* __restrict__ deg, int* __restrict__ part, int N){
    __shared__ int red[256];
    const int t = threadIdx.x;
    int base = blockIdx.x*1024;
    int s = 0;
    #pragma unroll
    for (int j=0;j<4;j++){ int i = base + j*256 + t; s += (i<N)?deg[i]:0; }
    red[t]=s; __syncthreads();
    #pragma unroll
    for (int off=128; off>0; off>>=1){ if (t<off) red[t]+=red[t+off]; __syncthreads(); }
    if (t==0) part[blockIdx.x]=red[0];
}
__global__ __launch_bounds__(256) void scan_top(int* __restrict__ part, int nb){
    __shared__ int buf[256];
    const int t = threadIdx.x;
    int v = (t < nb) ? part[t] : 0;
    buf[t] = v;
    __syncthreads();
    #pragma unroll
    for (int off=1; off<256; off<<=1){
        int u = (t>=off)?buf[t-off]:0;
        __syncthreads();
        buf[t] += u;
        __syncthreads();
    }
    if (t < nb) part[t] = buf[t] - v;
}
// scan_final also precomputes the per-node tile-boundary flag and packs it into deg's sign bit.
__global__ __launch_bounds__(256) void scan_final(int* __restrict__ deg, const int* __restrict__ part,
                                                  int* __restrict__ cur, int N){
    __shared__ int tsum[256];
    const int t = threadIdx.x;
    int i0 = blockIdx.x*1024 + t*4;
    int a0 = (i0+0<N)?deg[i0+0]:0;
    int a1 = (i0+1<N)?deg[i0+1]:0;
    int a2 = (i0+2<N)?deg[i0+2]:0;
    int a3 = (i0+3<N)?deg[i0+3]:0;
    int s = a0+a1+a2+a3;
    tsum[t]=s; __syncthreads();
    #pragma unroll
    for (int off=1; off<256; off<<=1){
        int u = (t>=off)?tsum[t-off]:0;
        __syncthreads();
        tsum[t]+=u;
        __syncthreads();
    }
    int excl = tsum[t]-s + part[blockIdx.x];
    int e0 = excl, e1 = excl+a0, e2 = excl+a0+a1, e3 = excl+a0+a1+a2;
    if (i0+0<N){ cur[i0+0]=e0; if (a0>0 && (e0>>7)!=((e0+a0-1)>>7)) deg[i0+0]=a0|0x80000000; }
    if (i0+1<N){ cur[i0+1]=e1; if (a1>0 && (e1>>7)!=((e1+a1-1)>>7)) deg[i0+1]=a1|0x80000000; }
    if (i0+2<N){ cur[i0+2]=e2; if (a2>0 && (e2>>7)!=((e2+a2-1)>>7)) deg[i0+2]=a2|0x80000000; }
    if (i0+3<N){ cur[i0+3]=e3; if (a3>0 && (e3>>7)!=((e3+a3-1)>>7)) deg[i0+3]=a3|0x80000000; }
}

__global__ __launch_bounds__(256) void scatter_kernel(
    const int* __restrict__ send, const int* __restrict__ rec, const float* __restrict__ pos,
    int* __restrict__ cur, int2* __restrict__ sd_s, int* __restrict__ rec_s, int E)
{
    int e = blockIdx.x*256 + threadIdx.x;
    if (e >= E) return;
    int s = send[e], r = rec[e];
    int p = atomicAdd(&cur[r], 1);
    float dx = pos[3*s]   - pos[3*r];
    float dy = pos[3*s+1] - pos[3*r+1];
    float dz = pos[3*s+2] - pos[3*r+2];
    float d = sqrtf(dx*dx + dy*dy + dz*dz);
    sd_s[p] = make_int2(s, __float_as_int(d));
    rec_s[p] = r;
    // after this kernel: cur[r] = end offset of node r's run; deg[r] = run length | bndflag
}

// ---------------- edge: gather SR, silu into B-frags, GEMM2, segment-reduce ----------------
// R11: 512 threads / 8 waves per TILE=128 block, one 16-edge group per wave
// (was 4 waves x 32 edges). __launch_bounds__(512,8) -> 4 blocks/CU = 32 waves/CU
// (vs 20): +60% latency hiding while the in-flight gather footprint SHRINKS
// (4x128=512 edges/CU vs 5x128=640) — decouples the R1 "more blocks thrash L2"
// failure from wave-level parallelism. Total VALU work unchanged; weight
// A-fragment loads double but are L1-broadcast hits.
template<bool FULL>
static __device__ __forceinline__ void edge_body(
    const short* __restrict__ SR,
    const int2* __restrict__ sd_s, const int* __restrict__ rec_s,
    const float* __restrict__ w1r192,
    const short* __restrict__ w2sw, const float* __restrict__ b2,
    float* __restrict__ aggr, float* __restrict__ stageA, float* __restrict__ stageB, int E,
    short* msgS, int* recS, int* startIdxS, int* wcntS)
{
    const int t  = threadIdx.x;
    const int e0 = blockIdx.x * TILE;
    const int lane = t & 63;
    const int wv   = t >> 6;         // 0..7
    const int e_lo = wv * 16;        // wave's 16-edge group
    const int col  = lane & 15;
    const int quad = lane >> 4;
    const int frow = quad * 4;
    const float4v fzero = {0.f,0.f,0.f,0.f};
    const int emax = E - 1;

    // ---- S-side staging: 24 wave-instrs over 8 waves (3 each), chunk-major [cc][e] ----
    // slot byte = cc*2048 + e*16 ; idx = i*8+wv in 0..23 ; cc = idx>>1 ; e = (idx&1)*64+lane
    int seStage[3];
    const int* sdp = (const int*)sd_s;
    #pragma unroll
    for (int i=0;i<3;i++){
        int idx = i*8 + wv;
        int e  = ((idx & 1) << 6) + lane;
        int ec = e0 + e;
        if (!FULL) ec = min(ec, emax);
        seStage[i] = sdp[2*ec];
    }
    #pragma unroll
    for (int i=0;i<3;i++){
        int idx = i*8 + wv;
        int cc  = idx >> 1;
        const short* src = SR + (size_t)seStage[i]*192 + cc*8;
        gload_lds16(src, msgS + idx*512);   // LDS byte base idx*1024, +lane*16
    }

    // ---- own-edge metadata + cache-hot rec-side gathers (registers) ----
    int ecm = e0 + e_lo + col;
    if (!FULL) ecm = min(ecm, emax);
    int2 sd = sd_s[ecm];
    float dd = __int_as_float(sd.y);
    int re = rec_s[ecm];
    uint4v Rvu[3];
    #pragma unroll
    for (int ks=0; ks<3; ++ks){
        int f0 = ks*32 + quad*8;
        Rvu[ks] = *(const uint4v*)(SR + (size_t)re*192 + 96 + f0);
    }

    // ---- segment table from global reads (threads 0..127 only) ----
    int myRec = 0;
    bool flag = false;
    if (t < TILE) {
        int e = e0 + t;
        if (!FULL) e = min(e, emax);
        myRec = rec_s[e];
        recS[t] = myRec;
        int ep = e0 + t - 1;
        if (!FULL && ep > emax) ep = emax;
        flag = (t == 0) || (myRec != rec_s[ep]);
    }
    unsigned long long bmask = __ballot(flag ? 1 : 0);
    int pre = __popcll(bmask & ((1ull << (t & 63)) - 1ull));
    if (t < TILE && (t & 63) == 0) wcntS[t >> 6] = __popcll(bmask);

    const bool firstB = (e0 > 0) && (rec_s[e0-1] == rec_s[e0]);
    const bool lastB  = (e0 + TILE < E) && (rec_s[e0 + TILE] == rec_s[FULL ? (e0+TILE-1) : min(e0+TILE-1, emax)]);

    __syncthreads();   // staging drained (vmcnt0) + recS/wcntS visible

    if (flag) startIdxS[pre + ((t >> 6) ? wcntS[0] : 0)] = t;
    if (t == 0) startIdxS[wcntS[0] + wcntS[1]] = TILE;

    // ---- build B-fragments: S from LDS staging (chunk-major), R from registers ----
    short8 frag[3];
    {
        float2v d2 = {dd, dd};
        int e_local = e_lo + col;
        #pragma unroll
        for (int ks=0; ks<3; ++ks){
            int f0 = ks*32 + quad*8;
            const float2v* wp = (const float2v*)(w1r192 + f0);
            uint4v su = *(const uint4v*)(msgS + (ks*4+quad)*1024 + e_local*8);
            uint4v ru = Rvu[ks];
            uint4v fo;
            #pragma unroll
            for (int p=0;p<4;p++){
                float2v w2 = wp[p];
                unsigned us = su[p], ur = ru[p];
                float2v s2 = { __uint_as_float(us << 16), __uint_as_float(us & 0xffff0000u) };
                float2v r2 = { __uint_as_float(ur << 16), __uint_as_float(ur & 0xffff0000u) };
                float2v v = s2 + r2 + d2*w2;
                fo[p] = silu2_pack(v);
            }
            short8 fr;
            __builtin_memcpy(&fr, &fo, 16);
            frag[ks] = fr;
        }
    }
    __syncthreads();   // all S ds_reads done before epilogue overwrites msgS

    float4v acc2[6];
    #pragma unroll
    for (int n=0;n<6;n++) acc2[n] = fzero;

    const short8* w2f = (const short8*)w2sw;
    #pragma unroll
    for (int ks = 0; ks < 3; ++ks) {
        #pragma unroll
        for (int mt = 0; mt < 6; ++mt) {
            short8 a = w2f[(ks*6+mt)*64 + lane];
            acc2[mt] = __builtin_amdgcn_mfma_f32_16x16x32_bf16(a, frag[ks], acc2[mt], 0, 0, 0);
        }
    }
    float4v b2v[6];
    #pragma unroll
    for (int mt=0; mt<6; ++mt) b2v[mt] = *(const float4v*)(b2 + mt*16 + frow);

    {
        int e = e_lo + col;
        bool valid = FULL || ((e0 + e) < E);
        #pragma unroll
        for (int mt=0; mt<6; ++mt){
            float2v aLo = *(const float2v*)&acc2[mt];
            float2v aHi = *((const float2v*)&acc2[mt] + 1);
            float2v bLo = *(const float2v*)&b2v[mt];
            float2v bHi = *((const float2v*)&b2v[mt] + 1);
            unsigned ulo = silu2_pack(aLo + bLo);
            unsigned uhi = silu2_pack(aHi + bHi);
            if (!valid){ ulo = 0u; uhi = 0u; }
            uint2v st = {ulo, uhi};
            *(uint2v*)(msgS + e*104 + mt*16 + frow) = st;
        }
    }
    __syncthreads();

    // segment-sum: 4-col items (nseg*24); packed-pair unpack + pk accumulate
    const int nseg = wcntS[0] + wcntS[1];
    const int items = nseg * 24;
    for (int item = t; item < items; item += 512){
        int s  = item / 24;
        int fg = item - s*24;
        int r0 = startIdxS[s], r1 = startIdxS[s+1];
        float2v s01 = {0.f,0.f}, s23 = {0.f,0.f};
        for (int r = r0; r < r1; ++r){
            const unsigned* pp = (const unsigned*)(msgS + r*104 + fg*4);
            unsigned p0 = pp[0], p1 = pp[1];
            float2v a0 = { __uint_as_float(p0 << 16), __uint_as_float(p0 & 0xffff0000u) };
            float2v a1 = { __uint_as_float(p1 << 16), __uint_as_float(p1 & 0xffff0000u) };
            s01 += a0; s23 += a1;
        }
        int node = recS[r0];
        float* dstp;
        if (s == 0 && firstB)            dstp = stageB + (size_t)node*HDIM + fg*4;  // head partial
        else if (s == nseg-1 && lastB)   dstp = stageA + (size_t)node*HDIM + fg*4;  // tail partial
        else                             dstp = aggr   + (size_t)node*HDIM + fg*4;  // complete row
        float4v v = {s01[0], s01[1], s23[0], s23[1]};
        *(float4v*)(dstp) = v;
    }
}

__global__ __launch_bounds__(512,8) void edge_kernel(
    const short* __restrict__ SR,
    const int2* __restrict__ sd_s, const int* __restrict__ rec_s,
    const float* __restrict__ w1r192,
    const short* __restrict__ w2sw, const float* __restrict__ b2,
    float* __restrict__ aggr, float* __restrict__ stageA, float* __restrict__ stageB, int E)
{
    __shared__ short msgS[TILE*104];     // phase A: S-staging (24576 B used); phase B: msg (26624 B)
    __shared__ int   recS[TILE];
    __shared__ int   startIdxS[TILE+1];
    __shared__ int   wcntS[2];
    const int e0 = blockIdx.x * TILE;
    if (e0 + TILE <= E)
        edge_body<true >(SR, sd_s, rec_s, w1r192, w2sw, b2, aggr, stageA, stageB, E, msgS, recS, startIdxS, wcntS);
    else
        edge_body<false>(SR, sd_s, rec_s, w1r192, w2sw, b2, aggr, stageA, stageB, E, msgS, recS, startIdxS, wcntS);
}

// ---------------- node update: hbf += MLP([h,aggr]) (bf16 residual); SR tail or prepool tail ----------------
// Zero-barrier, zero-staging main path (R9): all LDS producer->consumer pairs are
// intra-wave; GEMM1 B-fragments load directly from global.
__global__ __launch_bounds__(256,3) void update_kernel(
    short* __restrict__ hbf, const float* __restrict__ aggr,
    const float* __restrict__ stageA, const float* __restrict__ stageB,
    const int* __restrict__ deg,
    const short* __restrict__ w1sw, const float* __restrict__ b1,
    const short* __restrict__ w2sw, const float* __restrict__ b2,
    const short* __restrict__ w1sr_next, const float* __restrict__ msgb1_next,
    short* __restrict__ SR,
    const short* __restrict__ pw1, const float* __restrict__ pb1,
    const short* __restrict__ pw2, const float* __restrict__ pb2,
    const int* __restrict__ batch, float* __restrict__ pooled, int N)
{
    __shared__ short stateS[NTILE*208];   // region0=[0,6656) region1=[6656,13312) shorts
    __shared__ int   batchS[NTILE];
    __shared__ int   startIdxS[NTILE+1];
    __shared__ int   nsegS;
    const int t  = threadIdx.x;
    const int n0 = blockIdx.x * NTILE;
    const int lane = t & 63;
    const int wv   = t >> 6;        // 0..3
    const int rb   = wv * 16;       // wave's row base
    const int col  = lane & 15;
    const int quad = lane >> 4;
    const int koff = quad * 8;
    const int frow = quad * 4;
    const float4v fzero = {0.f,0.f,0.f,0.f};

    const int nodeRaw = n0 + rb + col;
    const bool valid  = nodeRaw < N;
    const int  node   = valid ? nodeRaw : N - 1;
    const size_t hbase = (size_t)node * HDIM;

    // ---- direct B-fragments (no LDS staging, no barrier) ----
    short8 bh[3];
    #pragma unroll
    for (int ks=0; ks<3; ++ks)
        bh[ks] = *(const short8*)(hbf + hbase + ks*32 + koff);

    const bool bnd = deg[node] < 0;    // precomputed tile-boundary flag
    short8 ba[3];
    #pragma unroll
    for (int ks=0; ks<3; ++ks){
        size_t b = hbase + ks*32 + koff;
        float4v a0, a1;
        if (bnd){
            a0 = *(const float4v*)(stageA + b)     + *(const float4v*)(stageB + b);
            a1 = *(const float4v*)(stageA + b + 4) + *(const float4v*)(stageB + b + 4);
        } else {
            a0 = *(const float4v*)(aggr + b);
            a1 = *(const float4v*)(aggr + b + 4);
        }
        short8 s8;
        s8[0]=f2bf(a0[0]); s8[1]=f2bf(a0[1]); s8[2]=f2bf(a0[2]); s8[3]=f2bf(a0[3]);
        s8[4]=f2bf(a1[0]); s8[5]=f2bf(a1[1]); s8[6]=f2bf(a1[2]); s8[7]=f2bf(a1[3]);
        ba[ks] = s8;
    }

    float4v acc[6];
    #pragma unroll
    for (int n=0;n<6;n++) acc[n] = fzero;

    const short8* w1f = (const short8*)w1sw;
    #pragma unroll
    for (int ks = 0; ks < 6; ++ks) {
        short8 bb = (ks < 3) ? bh[ks] : ba[ks-3];
        #pragma unroll
        for (int mt = 0; mt < 6; ++mt) {
            short8 a = w1f[(ks*6+mt)*64 + lane];
            acc[mt] = __builtin_amdgcn_mfma_f32_16x16x32_bf16(a, bb, acc[mt], 0, 0, 0);
        }
    }
    float4v b1v[6];
    #pragma unroll
    for (int mt=0; mt<6; ++mt) b1v[mt] = *(const float4v*)(b1 + mt*16 + frow);

    short* t1S = stateS;   // stride 104, region0; wave-private rows rb..rb+15
    {
        int e = rb + col;
        #pragma unroll
        for (int mt=0; mt<6; ++mt){
            short4v sv;
            #pragma unroll
            for (int r=0;r<4;r++) sv[r] = f2bf(silu_f(acc[mt][r] + b1v[mt][r]));
            *(short4v*)(t1S + e*104 + mt*16 + frow) = sv;
        }
    }
    // no barrier: GEMM2 reads only this wave's rows (per-wave DS in-order)

    float4v acc2[6];
    #pragma unroll
    for (int n=0;n<6;n++) acc2[n] = fzero;

    const short8* w2f = (const short8*)w2sw;
    #pragma unroll
    for (int ks = 0; ks < 3; ++ks) {
        short8 bb = *(const short8*)(t1S + (rb+col)*104 + ks*32 + koff);
        #pragma unroll
        for (int mt = 0; mt < 6; ++mt) {
            short8 a = w2f[(ks*6+mt)*64 + lane];
            acc2[mt] = __builtin_amdgcn_mfma_f32_16x16x32_bf16(a, bb, acc2[mt], 0, 0, 0);
        }
    }
    float4v b2v[6];
    #pragma unroll
    for (int mt=0; mt<6; ++mt) b2v[mt] = *(const float4v*)(b2 + mt*16 + frow);

    {
        int erow = rb + col;
        size_t base = (size_t)node*HDIM;
        #pragma unroll
        for (int mt=0; mt<6; ++mt){
            int f0 = mt*16 + frow;
            short4v ov = {0,0,0,0};
            if (valid) ov = *(const short4v*)(hbf + base + f0);
            float4v o;
            #pragma unroll
            for (int r=0;r<4;r++) o[r] = bf2f(ov[r]) + acc2[mt][r] + b2v[mt][r];
            short4v sv = {f2bf(o[0]), f2bf(o[1]), f2bf(o[2]), f2bf(o[3])};
            if (valid) *(short4v*)(hbf + base + f0) = sv;
            *(short4v*)(stateS + erow*104 + f0) = sv;   // new h (overwrites own t1 rows, already consumed)
        }
    }

    if (w1sr_next) {   // SR tail for next layer (l<3): intra-wave reads, no barrier
        float4v accS[12];
        #pragma unroll
        for (int n=0;n<12;n++) accS[n] = fzero;

        const short8* wsf = (const short8*)w1sr_next;
        #pragma unroll
        for (int ks = 0; ks < 3; ++ks) {
            short8 bb = *(const short8*)(stateS + (rb+col)*104 + ks*32 + koff);
            #pragma unroll
            for (int mt = 0; mt < 12; ++mt) {
                short8 a = wsf[(ks*12+mt)*64 + lane];
                accS[mt] = __builtin_amdgcn_mfma_f32_16x16x32_bf16(a, bb, accS[mt], 0, 0, 0);
            }
        }
        float4v bnv[6];
        #pragma unroll
        for (int mt=0; mt<6; ++mt) bnv[mt] = *(const float4v*)(msgb1_next + mt*16 + frow);

        if (valid) {
            size_t sbase = (size_t)node*192;
            #pragma unroll
            for (int mt=0; mt<12; ++mt){
                float4v o = accS[mt];
                if (mt < 6) { o[0]+=bnv[mt][0]; o[1]+=bnv[mt][1]; o[2]+=bnv[mt][2]; o[3]+=bnv[mt][3]; }
                short4v sv = {f2bf(o[0]), f2bf(o[1]), f2bf(o[2]), f2bf(o[3])};
                *(short4v*)(SR + sbase + mt*16 + frow) = sv;
            }
        }
    } else if (pw1) {   // fused pre-MLP + pooling tail (l=3): keeps cross-wave barriers
        if (t < NTILE) {
            int nd = n0 + t;
            batchS[t] = batch[nd < N ? nd : N-1];
        }
        __syncthreads();   // batchS visible

        bool flag = false;
        if (t < NTILE) flag = (t == 0) || (batchS[t] != batchS[t-1]);
        unsigned long long bm = __ballot(flag ? 1 : 0);
        if (t < NTILE) {
            int pre = __popcll(bm & ((1ull << t) - 1ull));
            if (flag) startIdxS[pre] = t;
            if (t == 0) nsegS = __popcll(bm);
        }

        float4v accp[6];
        #pragma unroll
        for (int n=0;n<6;n++) accp[n] = fzero;

        const short8* pw1f = (const short8*)pw1;
        #pragma unroll
        for (int ks = 0; ks < 3; ++ks) {
            short8 bb = *(const short8*)(stateS + (rb+col)*104 + ks*32 + koff);
            #pragma unroll
            for (int mt = 0; mt < 6; ++mt) {
                short8 a = pw1f[(ks*6+mt)*64 + lane];
                accp[mt] = __builtin_amdgcn_mfma_f32_16x16x32_bf16(a, bb, accp[mt], 0, 0, 0);
            }
        }
        float4v pb1v[6];
        #pragma unroll
        for (int mt=0; mt<6; ++mt) pb1v[mt] = *(const float4v*)(pb1 + mt*16 + frow);

        short* t1p = stateS + NTILE*104;   // region1; wave-private rows
        {
            int e = rb + col;
            #pragma unroll
            for (int mt=0; mt<6; ++mt){
                short4v sv;
                #pragma unroll
                for (int r=0;r<4;r++) sv[r] = f2bf(silu_f(accp[mt][r] + pb1v[mt][r]));
                *(short4v*)(t1p + e*104 + mt*16 + frow) = sv;
            }
        }

        float4v accq[6];
        #pragma unroll
        for (int n=0;n<6;n++) accq[n] = fzero;

        const short8* pw2f = (const short8*)pw2;
        #pragma unroll
        for (int ks = 0; ks < 3; ++ks) {
            short8 bb = *(const short8*)(t1p + (rb+col)*104 + ks*32 + koff);
            #pragma unroll
            for (int mt = 0; mt < 6; ++mt) {
                short8 a = pw2f[(ks*6+mt)*64 + lane];
                accq[mt] = __builtin_amdgcn_mfma_f32_16x16x32_bf16(a, bb, accq[mt], 0, 0, 0);
            }
        }
        float4v pb2v[6];
        #pragma unroll
        for (int mt=0; mt<6; ++mt) pb2v[mt] = *(const float4v*)(pb2 + mt*16 + frow);
        __syncthreads();   // ALL waves done reading stateS/t1p; msgS overwrites both regions

        float* msgS = (float*)stateS;   // stride 100 floats, 25600 B
        {
            int e = rb + col;
            #pragma unroll
            for (int mt=0; mt<6; ++mt){
                float4v v;
                #pragma unroll
                for (int r=0;r<4;r++){
                    float u = accq[mt][r] + pb2v[mt][r];
                    v[r] = valid ? u : 0.0f;
                }
                *(float4v*)(msgS + e*100 + mt*16 + frow) = v;
            }
        }
        __syncthreads();

        const int nseg = nsegS;
        if (t == 0) startIdxS[nseg] = NTILE;
        __syncthreads();

        const int items = nseg * 24;
        for (int item = t; item < items; item += 256){
            int s  = item / 24;
            int fg = item - s*24;
            int r0 = startIdxS[s], r1 = startIdxS[s+1];
            float4v sum = fzero;
            for (int r = r0; r < r1; ++r) sum += *(const float4v*)(msgS + r*100 + fg*4);
            float* dstp = pooled + (size_t)batchS[r0]*HDIM + fg*4;
            atomicAdd(dstp+0, sum[0]);
            atomicAdd(dstp+1, sum[1]);
            atomicAdd(dstp+2, sum[2]);
            atomicAdd(dstp+3, sum[3]);
        }
    }
}

// ---------------- embed (NTILE=64, 256 threads) ----------------
// Parallel staging (all 256 threads) + single barrier; t1/new-h/SR phases are
// intra-wave -> no barriers.
__global__ __launch_bounds__(256,3) void embed_kernel(
    const float* __restrict__ x, const float* __restrict__ pe,
    const short* __restrict__ w1sw, const float* __restrict__ b1,
    const short* __restrict__ w2sw, const float* __restrict__ b2,
    short* __restrict__ hbf,
    const short* __restrict__ w1sr0, const float* __restrict__ msgb1_0,
    short* __restrict__ SR, int N)
{
    __shared__ short stateS[NTILE*72];    // 9216 B (k 0..63 used)
    __shared__ short t1S[NTILE*104];      // 13312 B
    const int t  = threadIdx.x;
    const int n0 = blockIdx.x * NTILE;

    // parallel staging: item = (row = t>>2, k0 = (t&3)*16); 256 items cover 64x4
    {
        int row  = t >> 2;
        int k0   = (t & 3) << 4;
        int nodeS = n0 + row;
        short tmp[16];
        if (nodeS < N && k0 < 48) {
            const float* xr  = x  + (size_t)nodeS*11;
            const float* per = pe + (size_t)nodeS*24;
            #pragma unroll
            for (int j=0;j<16;j++){
                int k = k0 + j;
                float v = 0.f;
                if (k < 11)      v = xr[k];
                else if (k < 35) v = per[k-11];
                tmp[j] = f2bf(v);
            }
        } else {
            #pragma unroll
            for (int j=0;j<16;j++) tmp[j] = 0;
        }
        #pragma unroll
        for (int j=0;j<4;j++)
            *(short4v*)(stateS + row*72 + k0 + j*4) = *(short4v*)&tmp[j*4];
    }
    __syncthreads();   // cross-wave staging -> the ONE barrier

    const int lane = t & 63;
    const int wv   = t >> 6;        // 0..3
    const int rb   = wv * 16;
    const int col  = lane & 15;
    const int quad = lane >> 4;
    const int koff = quad * 8;
    const int frow = quad * 4;
    const float4v fzero = {0.f,0.f,0.f,0.f};

    float4v acc[6];
    #pragma unroll
    for (int n=0;n<6;n++) acc[n] = fzero;

    const short8* w1f = (const short8*)w1sw;
    #pragma unroll
    for (int ks = 0; ks < 2; ++ks) {
        short8 bb = *(const short8*)(stateS + (rb+col)*72 + ks*32 + koff);
        #pragma unroll
        for (int mt = 0; mt < 6; ++mt) {
            short8 a = w1f[(ks*6+mt)*64 + lane];
            acc[mt] = __builtin_amdgcn_mfma_f32_16x16x32_bf16(a, bb, acc[mt], 0, 0, 0);
        }
    }
    float4v b1v[6];
    #pragma unroll
    for (int mt=0; mt<6; ++mt) b1v[mt] = *(const float4v*)(b1 + mt*16 + frow);

    {
        int e = rb + col;
        #pragma unroll
        for (int mt=0; mt<6; ++mt){
            short4v sv;
            #pragma unroll
            for (int r=0;r<4;r++) sv[r] = f2bf(silu_f(acc[mt][r] + b1v[mt][r]));
            *(short4v*)(t1S + e*104 + mt*16 + frow) = sv;
        }
    }
    // no barrier: t1 rows rb..rb+15 are wave-private (per-wave DS in-order)

    float4v acc2[6];
    #pragma unroll
    for (int n=0;n<6;n++) acc2[n] = fzero;

    const short8* w2f = (const short8*)w2sw;
    #pragma unroll
    for (int ks = 0; ks < 3; ++ks) {
        short8 bb = *(const short8*)(t1S + (rb+col)*104 + ks*32 + koff);
        #pragma unroll
        for (int mt = 0; mt < 6; ++mt) {
            short8 a = w2f[(ks*6+mt)*64 + lane];
            acc2[mt] = __builtin_amdgcn_mfma_f32_16x16x32_bf16(a, bb, acc2[mt], 0, 0, 0);
        }
    }
    float4v b2v[6];
    #pragma unroll
    for (int mt=0; mt<6; ++mt) b2v[mt] = *(const float4v*)(b2 + mt*16 + frow);
    // no barrier: new-h overwrites own wave's t1 rows (already consumed by own GEMM2)

    {
        int erow = rb + col;
        int node = n0 + erow;
        bool valid = node < N;
        size_t base = (size_t)node*HDIM;
        #pragma unroll
        for (int mt=0; mt<6; ++mt){
            int f0 = mt*16 + frow;
            float4v o;
            #pragma unroll
            for (int r=0;r<4;r++) o[r] = acc2[mt][r] + b2v[mt][r];
            short4v sv = {f2bf(o[0]), f2bf(o[1]), f2bf(o[2]), f2bf(o[3])};
            if (valid) *(short4v*)(hbf + base + f0) = sv;
            *(short4v*)(t1S + erow*104 + f0) = sv;
        }
    }
    // no barrier: SR reads own wave's rows

    // SR for layer 0
    float4v accS[12];
    #pragma unroll
    for (int n=0;n<12;n++) accS[n] = fzero;

    const short8* wsf = (const short8*)w1sr0;
    #pragma unroll
    for (int ks = 0; ks < 3; ++ks) {
        short8 bb = *(const short8*)(t1S + (rb+col)*104 + ks*32 + koff);
        #pragma unroll
        for (int mt = 0; mt < 12; ++mt) {
            short8 a = wsf[(ks*12+mt)*64 + lane];
            accS[mt] = __builtin_amdgcn_mfma_f32_16x16x32_bf16(a, bb, accS[mt], 0, 0, 0);
        }
    }
    float4v bnv[6];
    #pragma unroll
    for (int mt=0; mt<6; ++mt) bnv[mt] = *(const float4v*)(msgb1_0 + mt*16 + frow);

    {
        int node = n0 + rb + col;
        if (node < N) {
            size_t sbase = (size_t)node*192;
            #pragma unroll
            for (int mt=0; mt<12; ++mt){
                float4v o = accS[mt];
                if (mt < 6) { o[0]+=bnv[mt][0]; o[1]+=bnv[mt][1]; o[2]+=bnv[mt][2]; o[3]+=bnv[mt][3]; }
                short4v sv = {f2bf(o[0]), f2bf(o[1]), f2bf(o[2]), f2bf(o[3])};
                *(short4v*)(SR + sbase + mt*16 + frow) = sv;
            }
        }
    }
}

// ---------------- readout ----------------
__global__ __launch_bounds__(128) void readout_kernel(
    const float* __restrict__ pooled,
    const float* __restrict__ w1, const float* __restrict__ b1,
    const float* __restrict__ w2, const float* __restrict__ b2,
    float* __restrict__ out)
{
    __shared__ float red[128];
    const int g = blockIdx.x;
    const int t = threadIdx.x;
    float p = 0.0f;
    if (t < HDIM) {
        float acc = b1[t];
        for (int k = 0; k < HDIM; ++k)
            acc += pooled[(size_t)g*HDIM + k] * w1[(size_t)k*HDIM + t];
        acc = silu_f(acc);
        p = acc * w2[t];
    }
    red[t] = p;
    __syncthreads();
    for (int s = 64; s > 0; s >>= 1) {
        if (t < s) red[t] += red[t + s];
        __syncthreads();
    }
    if (t == 0) out[g] = red[0] + b2[0];
}

extern "C" void kernel_launch(void* const* d_in, const int* in_sizes, int n_in,
                              void* d_out, int out_size, void* d_ws, size_t ws_size,
                              hipStream_t stream)
{
    const float* x        = (const float*)d_in[0];
    const float* pos      = (const float*)d_in[1];
    const float* pe       = (const float*)d_in[2];
    const int*   ei       = (const int*)d_in[3];
    const int*   batch    = (const int*)d_in[4];
    const float* embed_w1 = (const float*)d_in[5];
    const float* embed_b1 = (const float*)d_in[6];
    const float* embed_w2 = (const float*)d_in[7];
    const float* embed_b2 = (const float*)d_in[8];
    const float* msg_w1   = (const float*)d_in[9];
    const float* msg_b1   = (const float*)d_in[10];
    const float* msg_w2   = (const float*)d_in[11];
    const float* msg_b2   = (const float*)d_in[12];
    const float* upd_w1   = (const float*)d_in[13];
    const float* upd_b1   = (const float*)d_in[14];
    const float* upd_w2   = (const float*)d_in[15];
    const float* upd_b2   = (const float*)d_in[16];
    const float* pre_w1   = (const float*)d_in[17];
    const float* pre_b1   = (const float*)d_in[18];
    const float* pre_w2   = (const float*)d_in[19];
    const float* pre_b2   = (const float*)d_in[20];
    const float* ro_w1    = (const float*)d_in[21];
    const float* ro_b1    = (const float*)d_in[22];
    const float* ro_w2    = (const float*)d_in[23];
    const float* ro_b2    = (const float*)d_in[24];

    const int E = in_sizes[3] / 2;
    const int N = in_sizes[4];
    const int G = out_size;

    char* ws = (char*)d_ws;
    size_t off = 0;
    auto alloc = [&](size_t bytes){ void* p = ws + off; off += (bytes + 255) & ~(size_t)255; return p; };
    short* hbf    = (short*)alloc((size_t)N*HDIM*2);
    float* aggr   = (float*)alloc((size_t)N*HDIM*4);
    float* stageA = (float*)alloc((size_t)N*HDIM*4);
    float* stageB = (float*)alloc((size_t)N*HDIM*4);
    float* pooled = (float*)alloc((size_t)G*HDIM*4);
    short* wsw    = (short*)alloc((size_t)59*3072*2);
    short* w1sr   = (short*)alloc((size_t)4*18432*2);
    short* SR     = (short*)alloc((size_t)N*192*2);
    int*   deg    = (int*)alloc((size_t)N*4);
    int*   cur    = (int*)alloc((size_t)N*4);
    int*   part   = (int*)alloc((size_t)256*4);
    int2*  sd_s   = (int2*)alloc((size_t)E*8);
    int*   rec_s  = (int*)alloc((size_t)E*4);

    hipMemsetAsync(deg, 0, (size_t)N*4, stream);   // must precede swizzle_all (hist phase)

    SwTable T;
    for (int jj=0;jj<22;jj++){ T.j[jj].src = embed_w1; T.j[jj].ck = 1<<30; T.j[jj].ks = 0; T.j[jj].ksrc = 0; }
    int ck = 0, ji = 0;
    auto add = [&](const float* s, int ks, int ksrc){
        T.j[ji].src = s; T.j[ji].ck = ck; T.j[ji].ks = ks; T.j[ji].ksrc = ksrc;
        ji++; ck += ks;
    };
    add(embed_w1, 2, 35);   // ck 0
    add(embed_w2, 3, 96);   // ck 2
    add(pre_w1,   3, 96);   // ck 5
    add(pre_w2,   3, 96);   // ck 8
    for (int l=0;l<4;l++) add(msg_w2 + (size_t)l*96*96,  3, 96);   // ck 11+3l
    for (int l=0;l<4;l++) add(upd_w1 + (size_t)l*192*96, 6, 192);  // ck 23+6l
    for (int l=0;l<4;l++) add(upd_w2 + (size_t)l*96*96,  3, 96);   // ck 47+3l
    const int total1 = 59*3072;
    const int total2 = 4*18432;
    const int nA = N*24;           // aggr float4s
    const int nP = G*24;           // pooled float4s
    const int totalAll = total1 + total2 + nA + nP + E;
    swizzle_all<<<(totalAll+255)/256, 256, 0, stream>>>(T, msg_w1, wsw, w1sr, total1, total2,
                                                       aggr, pooled, nA, nP, ei + E, deg, E);

    const int nbE256 = (E + 255) / 256;
    const int nbScan = (N + 1023) / 1024;
    scan_part<<<nbScan, 256, 0, stream>>>(deg, part, N);
    scan_top<<<1, 256, 0, stream>>>(part, nbScan);
    scan_final<<<nbScan, 256, 0, stream>>>(deg, part, cur, N);
    scatter_kernel<<<nbE256, 256, 0, stream>>>(ei, ei + E, pos, cur, sd_s, rec_s, E);

    const int nbN = (N + NTILE - 1) / NTILE;
    embed_kernel<<<nbN, 256, 0, stream>>>(x, pe, wsw + 0, embed_b1, wsw + 2*3072, embed_b2,
                                          hbf, w1sr, msg_b1, SR, N);

    const int nbE = (E + TILE - 1) / TILE;
    for (int l = 0; l < 4; ++l) {
        edge_kernel<<<nbE, 512, 0, stream>>>(SR, sd_s, rec_s,
            msg_w1 + (size_t)l*193*96 + (size_t)192*96,
            wsw + (11 + 3*l)*3072, msg_b2 + l*96, aggr, stageA, stageB, E);
        const short* w1sr_next  = (l < 3) ? (w1sr + (size_t)(l+1)*18432) : nullptr;
        const float* msgb1_next = (l < 3) ? (msg_b1 + (l+1)*96) : nullptr;
        const short* pw1 = (l == 3) ? (wsw + 5*3072) : nullptr;
        const float* pb1 = (l == 3) ? pre_b1 : nullptr;
        const short* pw2 = (l == 3) ? (wsw + 8*3072) : nullptr;
        const float* pb2 = (l == 3) ? pre_b2 : nullptr;
        update_kernel<<<nbN, 256, 0, stream>>>(hbf, aggr, stageA, stageB, deg,
            wsw + (23 + 6*l)*3072, upd_b1 + l*96,
            wsw + (47 + 3*l)*3072, upd_b2 + l*96,
            w1sr_next, msgb1_next, SR,
            pw1, pb1, pw2, pb2, batch, pooled, N);
    }

    readout_kernel<<<G, 128, 0, stream>>>(pooled, ro_w1, ro_b1, ro_w2, ro_b2, (float*)d_out);
}

// Round 12
// 707.217 us; speedup vs baseline: 1.0403x; 1.0403x over previous
//
#include <hip/hip_runtime.h>
#include <hip/hip_bf16.h>

#define HDIM 96
#define TILE 128
#define NTILE 64

typedef __attribute__((ext_vector_type(8))) short  short8;
typedef __attribute__((ext_vector_type(4))) short  short4v;
typedef __attribute__((ext_vector_type(4))) float  float4v;
typedef __attribute__((ext_vector_type(2))) float  float2v;
typedef __attribute__((ext_vector_type(4))) unsigned int uint4v;
typedef __attribute__((ext_vector_type(2))) unsigned int uint2v;

// fast bf16 round (round-half-away): 2 VALU inst vs ~5 for full RNE.
static __device__ __forceinline__ short f2bf(float f){
    unsigned u = __float_as_uint(f);
    return (short)((u + 0x8000u) >> 16);
}
static __device__ __forceinline__ float bf2f(short s){
    unsigned u = ((unsigned)(unsigned short)s) << 16;
    return __uint_as_float(u);
}
// fast silu: v * rcp(1+exp(-v)) — v_rcp_f32 is ~1ulp, fine at bf16 tolerance
static __device__ __forceinline__ float silu_f(float v){
    return v * __builtin_amdgcn_rcpf(1.0f + __expf(-v));
}
// packed-pair silu -> packed bf16 u32 (elem0 low 16, elem1 high 16); v_pk_* friendly.
static __device__ __forceinline__ unsigned silu2_pack(float2v v){
    float e0 = __expf(-v[0]);
    float e1 = __expf(-v[1]);
    float2v ep = {e0, e1};
    const float2v one2 = {1.0f, 1.0f};
    ep += one2;
    float2v q = { __builtin_amdgcn_rcpf(ep[0]), __builtin_amdgcn_rcpf(ep[1]) };
    float2v res = v * q;
    unsigned pa = __float_as_uint(res[0]) + 0x8000u;
    unsigned pb = __float_as_uint(res[1]) + 0x8000u;
    return __builtin_amdgcn_perm(pb, pa, 0x07060302);
}

// async global->LDS, 16B per lane, per-lane GLOBAL src, wave-uniform LDS base (+lane*16 in HW)
typedef __attribute__((address_space(1))) const unsigned int guint;
typedef __attribute__((address_space(3))) unsigned int luint;
static __device__ __forceinline__ void gload_lds16(const void* g, void* l){
    __builtin_amdgcn_global_load_lds((guint*)g, (luint*)l, 16, 0, 0);
}

// ---------------- weight swizzle + workspace zeroing + edge histogram (merged) ----------------
// hist phase is safe here because deg is zeroed by a hipMemsetAsync that PRECEDES
// this kernel in stream order.
struct SwJob { const float* src; int ck; int ks; int ksrc; };
struct SwTable { SwJob j[22]; };

__global__ __launch_bounds__(256) void swizzle_all(SwTable T, const float* __restrict__ msg_w1,
                                                   short* __restrict__ dst, short* __restrict__ dst2,
                                                   int total1, int total2,
                                                   float* __restrict__ aggrZ, float* __restrict__ pooledZ,
                                                   int nA, int nP,
                                                   const int* __restrict__ recH, int* __restrict__ deg, int E){
    int gid = blockIdx.x*256 + threadIdx.x;
    if (gid < total1) {
        int ksg = gid / 3072;
        int e   = gid % 3072;
        const float* src = T.j[0].src; int k0 = 0, ksrc = 0;
        #pragma unroll
        for (int jj = 0; jj < 22; ++jj){
            int s = T.j[jj].ck;
            if (ksg >= s && ksg < s + T.j[jj].ks){ src = T.j[jj].src; k0 = (ksg - s)*32; ksrc = T.j[jj].ksrc; }
        }
        int nt   = e >> 9;
        int rem  = e & 511;
        int lane = rem >> 3;
        int jx   = rem & 7;
        int k = k0 + ((lane >> 4) << 3) + jx;
        int f = nt*16 + (lane & 15);
        float v = (k < ksrc) ? src[(size_t)k*HDIM + f] : 0.0f;
        dst[gid] = f2bf(v);
    } else if (gid < total1 + total2) {
        int g2 = gid - total1;
        int layer = g2 / 18432;
        int e     = g2 % 18432;
        int ksg = e / 6144;
        int rem = e % 6144;
        int nt   = rem >> 9;
        int r2   = rem & 511;
        int lane = r2 >> 3;
        int jx   = r2 & 7;
        int k = ksg*32 + ((lane >> 4) << 3) + jx;     // 0..95
        int f = nt*16 + (lane & 15);                  // 0..191
        int row = (f < 96) ? k : (96 + k);
        int col = (f < 96) ? f : (f - 96);
        dst2[g2] = f2bf(msg_w1[(size_t)layer*193*96 + (size_t)row*96 + col]);
    } else if (gid < total1 + total2 + nA + nP) {
        int gz = gid - total1 - total2;
        const float4v z = {0.f,0.f,0.f,0.f};
        if (gz < nA)  ((float4v*)aggrZ)[gz] = z;
        else          ((float4v*)pooledZ)[gz - nA] = z;
    } else {
        int e = gid - total1 - total2 - nA - nP;
        if (e < E) atomicAdd(&deg[recH[e]], 1);
    }
}

// ---------------- edge sorting scans (counting sort by rec) ----------------
__global__ __launch_bounds__(256) void scan_part(const int* __restrict__ deg, int* __restrict__ part, int N){
    __shared__ int red[256];
    const int t = threadIdx.x;
    int base = blockIdx.x*1024;
    int s = 0;
    #pragma unroll
    for (int j=0;j<4;j++){ int i = base + j*256 + t; s += (i<N)?deg[i]:0; }
    red[t]=s; __syncthreads();
    #pragma unroll
    for (int off=128; off>0; off>>=1){ if (t<off) red[t]+=red[t+off]; __syncthreads(); }
    if (t==0) part[blockIdx.x]=red[0];
}
__global__ __launch_bounds__(256) void scan_top(int* __restrict__ part, int nb){
    __shared__ int buf[256];
    const int t = threadIdx.x;
    int v = (t < nb) ? part[t] : 0;
    buf[t] = v;
    __syncthreads();
    #pragma unroll
    for (int off=1; off<256; off<<=1){
        int u = (t>=off)?buf[t-off]:0;
        __syncthreads();
        buf[t] += u;
        __syncthreads();
    }
    if (t < nb) part[t] = buf[t] - v;
}
// scan_final also precomputes the per-node tile-boundary flag and packs it into deg's sign bit.
__global__ __launch_bounds__(256) void scan_final(int* __restrict__ deg, const int* __restrict__ part,
                                                  int* __restrict__ cur, int N){
    __shared__ int tsum[256];
    const int t = threadIdx.x;
    int i0 = blockIdx.x*1024 + t*4;
    int a0 = (i0+0<N)?deg[i0+0]:0;
    int a1 = (i0+1<N)?deg[i0+1]:0;
    int a2 = (i0+2<N)?deg[i0+2]:0;
    int a3 = (i0+3<N)?deg[i0+3]:0;
    int s = a0+a1+a2+a3;
    tsum[t]=s; __syncthreads();
    #pragma unroll
    for (int off=1; off<256; off<<=1){
        int u = (t>=off)?tsum[t-off]:0;
        __syncthreads();
        tsum[t]+=u;
        __syncthreads();
    }
    int excl = tsum[t]-s + part[blockIdx.x];
    int e0 = excl, e1 = excl+a0, e2 = excl+a0+a1, e3 = excl+a0+a1+a2;
    if (i0+0<N){ cur[i0+0]=e0; if (a0>0 && (e0>>7)!=((e0+a0-1)>>7)) deg[i0+0]=a0|0x80000000; }
    if (i0+1<N){ cur[i0+1]=e1; if (a1>0 && (e1>>7)!=((e1+a1-1)>>7)) deg[i0+1]=a1|0x80000000; }
    if (i0+2<N){ cur[i0+2]=e2; if (a2>0 && (e2>>7)!=((e2+a2-1)>>7)) deg[i0+2]=a2|0x80000000; }
    if (i0+3<N){ cur[i0+3]=e3; if (a3>0 && (e3>>7)!=((e3+a3-1)>>7)) deg[i0+3]=a3|0x80000000; }
}

__global__ __launch_bounds__(256) void scatter_kernel(
    const int* __restrict__ send, const int* __restrict__ rec, const float* __restrict__ pos,
    int* __restrict__ cur, int2* __restrict__ sd_s, int* __restrict__ rec_s, int E)
{
    int e = blockIdx.x*256 + threadIdx.x;
    if (e >= E) return;
    int s = send[e], r = rec[e];
    int p = atomicAdd(&cur[r], 1);
    float dx = pos[3*s]   - pos[3*r];
    float dy = pos[3*s+1] - pos[3*r+1];
    float dz = pos[3*s+2] - pos[3*r+2];
    float d = sqrtf(dx*dx + dy*dy + dz*dz);
    sd_s[p] = make_int2(s, __float_as_int(d));
    rec_s[p] = r;
    // after this kernel: cur[r] = end offset of node r's run; deg[r] = run length | bndflag
}

// ---------------- edge: gather SR, silu into B-frags, GEMM2, segment-reduce ----------------
// R12: reverted to the proven 4-wave/256-thread/5-block config (R11's 8-wave split
// regressed: VALUBusy 57->51, MfmaUtil 6.7->5.8, +15us — per-wave fixed overhead
// doubles and barrier stragglers grow; occupancy was never the binding constraint).
// New in R12: s_setprio(1) around the MFMA cluster, measured IN ISOLATION this
// time (R7 bundled it with the edat regression). Edge blocks are phase-diverse
// on a CU (5 independent blocks) — the regime where setprio measured +4-7%.
template<bool FULL>
static __device__ __forceinline__ void edge_body(
    const short* __restrict__ SR,
    const int2* __restrict__ sd_s, const int* __restrict__ rec_s,
    const float* __restrict__ w1r192,
    const short* __restrict__ w2sw, const float* __restrict__ b2,
    float* __restrict__ aggr, float* __restrict__ stageA, float* __restrict__ stageB, int E,
    short* msgS, int* recS, int* startIdxS, int* wcntS)
{
    const int t  = threadIdx.x;
    const int e0 = blockIdx.x * TILE;
    const int lane = t & 63;
    const int wv   = t >> 6;
    const int e_lo = wv * 32;
    const int col  = lane & 15;
    const int quad = lane >> 4;
    const int frow = quad * 4;
    const float4v fzero = {0.f,0.f,0.f,0.f};
    const int emax = E - 1;

    // ---- S-side staging: 24 wave-instrs, chunk-major [cc][e] layout ----
    int seStage[6];
    const int* sdp = (const int*)sd_s;
    #pragma unroll
    for (int i=0;i<6;i++){
        int idx = i*4 + wv;
        int e  = ((idx & 1) << 6) + lane;
        int ec = e0 + e;
        if (!FULL) ec = min(ec, emax);
        seStage[i] = sdp[2*ec];
    }
    #pragma unroll
    for (int i=0;i<6;i++){
        int idx = i*4 + wv;
        int cc  = idx >> 1;
        const short* src = SR + (size_t)seStage[i]*192 + cc*8;
        gload_lds16(src, msgS + idx*512);   // LDS byte base idx*1024, +lane*16
    }

    // ---- own-edge metadata + cache-hot rec-side gathers (registers) ----
    int re[2]; float dd[2];
    #pragma unroll
    for (int et=0; et<2; ++et){
        int ec = e0 + e_lo + et*16 + col;
        if (!FULL) ec = min(ec, emax);
        int2 sd = sd_s[ec];
        dd[et] = __int_as_float(sd.y);
        re[et] = rec_s[ec];
    }
    uint4v Rvu[2][3];
    #pragma unroll
    for (int et=0; et<2; ++et)
      #pragma unroll
      for (int ks=0; ks<3; ++ks){
        int f0 = ks*32 + quad*8;
        Rvu[et][ks] = *(const uint4v*)(SR + (size_t)re[et]*192 + 96 + f0);
      }

    // ---- segment table from global reads ----
    int myRec = 0;
    bool flag = false;
    if (t < TILE) {
        int e = e0 + t;
        if (!FULL) e = min(e, emax);
        myRec = rec_s[e];
        recS[t] = myRec;
        int ep = e0 + t - 1;
        if (!FULL && ep > emax) ep = emax;
        flag = (t == 0) || (myRec != rec_s[ep]);
    }
    unsigned long long bmask = __ballot(flag ? 1 : 0);
    int pre = __popcll(bmask & ((1ull << (t & 63)) - 1ull));
    if (t < TILE && (t & 63) == 0) wcntS[t >> 6] = __popcll(bmask);

    const bool firstB = (e0 > 0) && (rec_s[e0-1] == rec_s[e0]);
    const bool lastB  = (e0 + TILE < E) && (rec_s[e0 + TILE] == rec_s[FULL ? (e0+TILE-1) : min(e0+TILE-1, emax)]);

    __syncthreads();   // staging drained (vmcnt0) + recS/wcntS visible

    if (flag) startIdxS[pre + ((t >> 6) ? wcntS[0] : 0)] = t;
    if (t == 0) startIdxS[wcntS[0] + wcntS[1]] = TILE;

    // ---- build B-fragments: S from LDS staging (chunk-major), R from registers ----
    short8 frag[2][3];
    #pragma unroll
    for (int et=0; et<2; ++et){
        float2v d2 = {dd[et], dd[et]};
        int e_local = e_lo + et*16 + col;
        #pragma unroll
        for (int ks=0; ks<3; ++ks){
            int f0 = ks*32 + quad*8;
            const float2v* wp = (const float2v*)(w1r192 + f0);
            uint4v su = *(const uint4v*)(msgS + (ks*4+quad)*1024 + e_local*8);
            uint4v ru = Rvu[et][ks];
            uint4v fo;
            #pragma unroll
            for (int p=0;p<4;p++){
                float2v w2 = wp[p];
                unsigned us = su[p], ur = ru[p];
                float2v s2 = { __uint_as_float(us << 16), __uint_as_float(us & 0xffff0000u) };
                float2v r2 = { __uint_as_float(ur << 16), __uint_as_float(ur & 0xffff0000u) };
                float2v v = s2 + r2 + d2*w2;
                fo[p] = silu2_pack(v);
            }
            short8 fr;
            __builtin_memcpy(&fr, &fo, 16);
            frag[et][ks] = fr;
        }
    }
    __syncthreads();   // all S ds_reads done before epilogue overwrites msgS

    float4v acc2[2][6];
    #pragma unroll
    for (int i=0;i<2;i++)
      #pragma unroll
      for (int n=0;n<6;n++) acc2[i][n] = fzero;

    const short8* w2f = (const short8*)w2sw;
    __builtin_amdgcn_s_setprio(1);
    #pragma unroll
    for (int ks = 0; ks < 3; ++ks) {
        #pragma unroll
        for (int mt = 0; mt < 6; ++mt) {
            short8 a = w2f[(ks*6+mt)*64 + lane];
            acc2[0][mt] = __builtin_amdgcn_mfma_f32_16x16x32_bf16(a, frag[0][ks], acc2[0][mt], 0, 0, 0);
            acc2[1][mt] = __builtin_amdgcn_mfma_f32_16x16x32_bf16(a, frag[1][ks], acc2[1][mt], 0, 0, 0);
        }
    }
    __builtin_amdgcn_s_setprio(0);
    float4v b2v[6];
    #pragma unroll
    for (int mt=0; mt<6; ++mt) b2v[mt] = *(const float4v*)(b2 + mt*16 + frow);

    #pragma unroll
    for (int et=0; et<2; ++et){
        int e = e_lo + et*16 + col;
        bool valid = FULL || ((e0 + e) < E);
        #pragma unroll
        for (int mt=0; mt<6; ++mt){
            float2v aLo = *(const float2v*)&acc2[et][mt];
            float2v aHi = *((const float2v*)&acc2[et][mt] + 1);
            float2v bLo = *(const float2v*)&b2v[mt];
            float2v bHi = *((const float2v*)&b2v[mt] + 1);
            unsigned ulo = silu2_pack(aLo + bLo);
            unsigned uhi = silu2_pack(aHi + bHi);
            if (!valid){ ulo = 0u; uhi = 0u; }
            uint2v st = {ulo, uhi};
            *(uint2v*)(msgS + e*104 + mt*16 + frow) = st;
        }
    }
    __syncthreads();

    // segment-sum: 4-col items (nseg*24); packed-pair unpack + pk accumulate
    const int nseg = wcntS[0] + wcntS[1];
    const int items = nseg * 24;
    for (int item = t; item < items; item += 256){
        int s  = item / 24;
        int fg = item - s*24;
        int r0 = startIdxS[s], r1 = startIdxS[s+1];
        float2v s01 = {0.f,0.f}, s23 = {0.f,0.f};
        for (int r = r0; r < r1; ++r){
            const unsigned* pp = (const unsigned*)(msgS + r*104 + fg*4);
            unsigned p0 = pp[0], p1 = pp[1];
            float2v a0 = { __uint_as_float(p0 << 16), __uint_as_float(p0 & 0xffff0000u) };
            float2v a1 = { __uint_as_float(p1 << 16), __uint_as_float(p1 & 0xffff0000u) };
            s01 += a0; s23 += a1;
        }
        int node = recS[r0];
        float* dstp;
        if (s == 0 && firstB)            dstp = stageB + (size_t)node*HDIM + fg*4;  // head partial
        else if (s == nseg-1 && lastB)   dstp = stageA + (size_t)node*HDIM + fg*4;  // tail partial
        else                             dstp = aggr   + (size_t)node*HDIM + fg*4;  // complete row
        float4v v = {s01[0], s01[1], s23[0], s23[1]};
        *(float4v*)(dstp) = v;
    }
}

__global__ __launch_bounds__(256,5) void edge_kernel(
    const short* __restrict__ SR,
    const int2* __restrict__ sd_s, const int* __restrict__ rec_s,
    const float* __restrict__ w1r192,
    const short* __restrict__ w2sw, const float* __restrict__ b2,
    float* __restrict__ aggr, float* __restrict__ stageA, float* __restrict__ stageB, int E)
{
    __shared__ short msgS[TILE*104];     // phase A: S-staging (24576 B used); phase B: msg (26624 B)
    __shared__ int   recS[TILE];
    __shared__ int   startIdxS[TILE+1];
    __shared__ int   wcntS[2];
    const int e0 = blockIdx.x * TILE;
    if (e0 + TILE <= E)
        edge_body<true >(SR, sd_s, rec_s, w1r192, w2sw, b2, aggr, stageA, stageB, E, msgS, recS, startIdxS, wcntS);
    else
        edge_body<false>(SR, sd_s, rec_s, w1r192, w2sw, b2, aggr, stageA, stageB, E, msgS, recS, startIdxS, wcntS);
}

// ---------------- node update: hbf += MLP([h,aggr]) (bf16 residual); SR tail or prepool tail ----------------
// Zero-barrier, zero-staging main path (R9): all LDS producer->consumer pairs are
// intra-wave; GEMM1 B-fragments load directly from global.
__global__ __launch_bounds__(256,3) void update_kernel(
    short* __restrict__ hbf, const float* __restrict__ aggr,
    const float* __restrict__ stageA, const float* __restrict__ stageB,
    const int* __restrict__ deg,
    const short* __restrict__ w1sw, const float* __restrict__ b1,
    const short* __restrict__ w2sw, const float* __restrict__ b2,
    const short* __restrict__ w1sr_next, const float* __restrict__ msgb1_next,
    short* __restrict__ SR,
    const short* __restrict__ pw1, const float* __restrict__ pb1,
    const short* __restrict__ pw2, const float* __restrict__ pb2,
    const int* __restrict__ batch, float* __restrict__ pooled, int N)
{
    __shared__ short stateS[NTILE*208];   // region0=[0,6656) region1=[6656,13312) shorts
    __shared__ int   batchS[NTILE];
    __shared__ int   startIdxS[NTILE+1];
    __shared__ int   nsegS;
    const int t  = threadIdx.x;
    const int n0 = blockIdx.x * NTILE;
    const int lane = t & 63;
    const int wv   = t >> 6;        // 0..3
    const int rb   = wv * 16;       // wave's row base
    const int col  = lane & 15;
    const int quad = lane >> 4;
    const int koff = quad * 8;
    const int frow = quad * 4;
    const float4v fzero = {0.f,0.f,0.f,0.f};

    const int nodeRaw = n0 + rb + col;
    const bool valid  = nodeRaw < N;
    const int  node   = valid ? nodeRaw : N - 1;
    const size_t hbase = (size_t)node * HDIM;

    // ---- direct B-fragments (no LDS staging, no barrier) ----
    short8 bh[3];
    #pragma unroll
    for (int ks=0; ks<3; ++ks)
        bh[ks] = *(const short8*)(hbf + hbase + ks*32 + koff);

    const bool bnd = deg[node] < 0;    // precomputed tile-boundary flag
    short8 ba[3];
    #pragma unroll
    for (int ks=0; ks<3; ++ks){
        size_t b = hbase + ks*32 + koff;
        float4v a0, a1;
        if (bnd){
            a0 = *(const float4v*)(stageA + b)     + *(const float4v*)(stageB + b);
            a1 = *(const float4v*)(stageA + b + 4) + *(const float4v*)(stageB + b + 4);
        } else {
            a0 = *(const float4v*)(aggr + b);
            a1 = *(const float4v*)(aggr + b + 4);
        }
        short8 s8;
        s8[0]=f2bf(a0[0]); s8[1]=f2bf(a0[1]); s8[2]=f2bf(a0[2]); s8[3]=f2bf(a0[3]);
        s8[4]=f2bf(a1[0]); s8[5]=f2bf(a1[1]); s8[6]=f2bf(a1[2]); s8[7]=f2bf(a1[3]);
        ba[ks] = s8;
    }

    float4v acc[6];
    #pragma unroll
    for (int n=0;n<6;n++) acc[n] = fzero;

    const short8* w1f = (const short8*)w1sw;
    #pragma unroll
    for (int ks = 0; ks < 6; ++ks) {
        short8 bb = (ks < 3) ? bh[ks] : ba[ks-3];
        #pragma unroll
        for (int mt = 0; mt < 6; ++mt) {
            short8 a = w1f[(ks*6+mt)*64 + lane];
            acc[mt] = __builtin_amdgcn_mfma_f32_16x16x32_bf16(a, bb, acc[mt], 0, 0, 0);
        }
    }
    float4v b1v[6];
    #pragma unroll
    for (int mt=0; mt<6; ++mt) b1v[mt] = *(const float4v*)(b1 + mt*16 + frow);

    short* t1S = stateS;   // stride 104, region0; wave-private rows rb..rb+15
    {
        int e = rb + col;
        #pragma unroll
        for (int mt=0; mt<6; ++mt){
            short4v sv;
            #pragma unroll
            for (int r=0;r<4;r++) sv[r] = f2bf(silu_f(acc[mt][r] + b1v[mt][r]));
            *(short4v*)(t1S + e*104 + mt*16 + frow) = sv;
        }
    }
    // no barrier: GEMM2 reads only this wave's rows (per-wave DS in-order)

    float4v acc2[6];
    #pragma unroll
    for (int n=0;n<6;n++) acc2[n] = fzero;

    const short8* w2f = (const short8*)w2sw;
    #pragma unroll
    for (int ks = 0; ks < 3; ++ks) {
        short8 bb = *(const short8*)(t1S + (rb+col)*104 + ks*32 + koff);
        #pragma unroll
        for (int mt = 0; mt < 6; ++mt) {
            short8 a = w2f[(ks*6+mt)*64 + lane];
            acc2[mt] = __builtin_amdgcn_mfma_f32_16x16x32_bf16(a, bb, acc2[mt], 0, 0, 0);
        }
    }
    float4v b2v[6];
    #pragma unroll
    for (int mt=0; mt<6; ++mt) b2v[mt] = *(const float4v*)(b2 + mt*16 + frow);

    {
        int erow = rb + col;
        size_t base = (size_t)node*HDIM;
        #pragma unroll
        for (int mt=0; mt<6; ++mt){
            int f0 = mt*16 + frow;
            short4v ov = {0,0,0,0};
            if (valid) ov = *(const short4v*)(hbf + base + f0);
            float4v o;
            #pragma unroll
            for (int r=0;r<4;r++) o[r] = bf2f(ov[r]) + acc2[mt][r] + b2v[mt][r];
            short4v sv = {f2bf(o[0]), f2bf(o[1]), f2bf(o[2]), f2bf(o[3])};
            if (valid) *(short4v*)(hbf + base + f0) = sv;
            *(short4v*)(stateS + erow*104 + f0) = sv;   // new h (overwrites own t1 rows, already consumed)
        }
    }

    if (w1sr_next) {   // SR tail for next layer (l<3): intra-wave reads, no barrier
        float4v accS[12];
        #pragma unroll
        for (int n=0;n<12;n++) accS[n] = fzero;

        const short8* wsf = (const short8*)w1sr_next;
        #pragma unroll
        for (int ks = 0; ks < 3; ++ks) {
            short8 bb = *(const short8*)(stateS + (rb+col)*104 + ks*32 + koff);
            #pragma unroll
            for (int mt = 0; mt < 12; ++mt) {
                short8 a = wsf[(ks*12+mt)*64 + lane];
                accS[mt] = __builtin_amdgcn_mfma_f32_16x16x32_bf16(a, bb, accS[mt], 0, 0, 0);
            }
        }
        float4v bnv[6];
        #pragma unroll
        for (int mt=0; mt<6; ++mt) bnv[mt] = *(const float4v*)(msgb1_next + mt*16 + frow);

        if (valid) {
            size_t sbase = (size_t)node*192;
            #pragma unroll
            for (int mt=0; mt<12; ++mt){
                float4v o = accS[mt];
                if (mt < 6) { o[0]+=bnv[mt][0]; o[1]+=bnv[mt][1]; o[2]+=bnv[mt][2]; o[3]+=bnv[mt][3]; }
                short4v sv = {f2bf(o[0]), f2bf(o[1]), f2bf(o[2]), f2bf(o[3])};
                *(short4v*)(SR + sbase + mt*16 + frow) = sv;
            }
        }
    } else if (pw1) {   // fused pre-MLP + pooling tail (l=3): keeps cross-wave barriers
        if (t < NTILE) {
            int nd = n0 + t;
            batchS[t] = batch[nd < N ? nd : N-1];
        }
        __syncthreads();   // batchS visible

        bool flag = false;
        if (t < NTILE) flag = (t == 0) || (batchS[t] != batchS[t-1]);
        unsigned long long bm = __ballot(flag ? 1 : 0);
        if (t < NTILE) {
            int pre = __popcll(bm & ((1ull << t) - 1ull));
            if (flag) startIdxS[pre] = t;
            if (t == 0) nsegS = __popcll(bm);
        }

        float4v accp[6];
        #pragma unroll
        for (int n=0;n<6;n++) accp[n] = fzero;

        const short8* pw1f = (const short8*)pw1;
        #pragma unroll
        for (int ks = 0; ks < 3; ++ks) {
            short8 bb = *(const short8*)(stateS + (rb+col)*104 + ks*32 + koff);
            #pragma unroll
            for (int mt = 0; mt < 6; ++mt) {
                short8 a = pw1f[(ks*6+mt)*64 + lane];
                accp[mt] = __builtin_amdgcn_mfma_f32_16x16x32_bf16(a, bb, accp[mt], 0, 0, 0);
            }
        }
        float4v pb1v[6];
        #pragma unroll
        for (int mt=0; mt<6; ++mt) pb1v[mt] = *(const float4v*)(pb1 + mt*16 + frow);

        short* t1p = stateS + NTILE*104;   // region1; wave-private rows
        {
            int e = rb + col;
            #pragma unroll
            for (int mt=0; mt<6; ++mt){
                short4v sv;
                #pragma unroll
                for (int r=0;r<4;r++) sv[r] = f2bf(silu_f(accp[mt][r] + pb1v[mt][r]));
                *(short4v*)(t1p + e*104 + mt*16 + frow) = sv;
            }
        }

        float4v accq[6];
        #pragma unroll
        for (int n=0;n<6;n++) accq[n] = fzero;

        const short8* pw2f = (const short8*)pw2;
        #pragma unroll
        for (int ks = 0; ks < 3; ++ks) {
            short8 bb = *(const short8*)(t1p + (rb+col)*104 + ks*32 + koff);
            #pragma unroll
            for (int mt = 0; mt < 6; ++mt) {
                short8 a = pw2f[(ks*6+mt)*64 + lane];
                accq[mt] = __builtin_amdgcn_mfma_f32_16x16x32_bf16(a, bb, accq[mt], 0, 0, 0);
            }
        }
        float4v pb2v[6];
        #pragma unroll
        for (int mt=0; mt<6; ++mt) pb2v[mt] = *(const float4v*)(pb2 + mt*16 + frow);
        __syncthreads();   // ALL waves done reading stateS/t1p; msgS overwrites both regions

        float* msgS = (float*)stateS;   // stride 100 floats, 25600 B
        {
            int e = rb + col;
            #pragma unroll
            for (int mt=0; mt<6; ++mt){
                float4v v;
                #pragma unroll
                for (int r=0;r<4;r++){
                    float u = accq[mt][r] + pb2v[mt][r];
                    v[r] = valid ? u : 0.0f;
                }
                *(float4v*)(msgS + e*100 + mt*16 + frow) = v;
            }
        }
        __syncthreads();

        const int nseg = nsegS;
        if (t == 0) startIdxS[nseg] = NTILE;
        __syncthreads();

        const int items = nseg * 24;
        for (int item = t; item < items; item += 256){
            int s  = item / 24;
            int fg = item - s*24;
            int r0 = startIdxS[s], r1 = startIdxS[s+1];
            float4v sum = fzero;
            for (int r = r0; r < r1; ++r) sum += *(const float4v*)(msgS + r*100 + fg*4);
            float* dstp = pooled + (size_t)batchS[r0]*HDIM + fg*4;
            atomicAdd(dstp+0, sum[0]);
            atomicAdd(dstp+1, sum[1]);
            atomicAdd(dstp+2, sum[2]);
            atomicAdd(dstp+3, sum[3]);
        }
    }
}

// ---------------- embed (NTILE=64, 256 threads) ----------------
// Parallel staging (all 256 threads) + single barrier; t1/new-h/SR phases are
// intra-wave -> no barriers.
__global__ __launch_bounds__(256,3) void embed_kernel(
    const float* __restrict__ x, const float* __restrict__ pe,
    const short* __restrict__ w1sw, const float* __restrict__ b1,
    const short* __restrict__ w2sw, const float* __restrict__ b2,
    short* __restrict__ hbf,
    const short* __restrict__ w1sr0, const float* __restrict__ msgb1_0,
    short* __restrict__ SR, int N)
{
    __shared__ short stateS[NTILE*72];    // 9216 B (k 0..63 used)
    __shared__ short t1S[NTILE*104];      // 13312 B
    const int t  = threadIdx.x;
    const int n0 = blockIdx.x * NTILE;

    // parallel staging: item = (row = t>>2, k0 = (t&3)*16); 256 items cover 64x4
    {
        int row  = t >> 2;
        int k0   = (t & 3) << 4;
        int nodeS = n0 + row;
        short tmp[16];
        if (nodeS < N && k0 < 48) {
            const float* xr  = x  + (size_t)nodeS*11;
            const float* per = pe + (size_t)nodeS*24;
            #pragma unroll
            for (int j=0;j<16;j++){
                int k = k0 + j;
                float v = 0.f;
                if (k < 11)      v = xr[k];
                else if (k < 35) v = per[k-11];
                tmp[j] = f2bf(v);
            }
        } else {
            #pragma unroll
            for (int j=0;j<16;j++) tmp[j] = 0;
        }
        #pragma unroll
        for (int j=0;j<4;j++)
            *(short4v*)(stateS + row*72 + k0 + j*4) = *(short4v*)&tmp[j*4];
    }
    __syncthreads();   // cross-wave staging -> the ONE barrier

    const int lane = t & 63;
    const int wv   = t >> 6;        // 0..3
    const int rb   = wv * 16;
    const int col  = lane & 15;
    const int quad = lane >> 4;
    const int koff = quad * 8;
    const int frow = quad * 4;
    const float4v fzero = {0.f,0.f,0.f,0.f};

    float4v acc[6];
    #pragma unroll
    for (int n=0;n<6;n++) acc[n] = fzero;

    const short8* w1f = (const short8*)w1sw;
    #pragma unroll
    for (int ks = 0; ks < 2; ++ks) {
        short8 bb = *(const short8*)(stateS + (rb+col)*72 + ks*32 + koff);
        #pragma unroll
        for (int mt = 0; mt < 6; ++mt) {
            short8 a = w1f[(ks*6+mt)*64 + lane];
            acc[mt] = __builtin_amdgcn_mfma_f32_16x16x32_bf16(a, bb, acc[mt], 0, 0, 0);
        }
    }
    float4v b1v[6];
    #pragma unroll
    for (int mt=0; mt<6; ++mt) b1v[mt] = *(const float4v*)(b1 + mt*16 + frow);

    {
        int e = rb + col;
        #pragma unroll
        for (int mt=0; mt<6; ++mt){
            short4v sv;
            #pragma unroll
            for (int r=0;r<4;r++) sv[r] = f2bf(silu_f(acc[mt][r] + b1v[mt][r]));
            *(short4v*)(t1S + e*104 + mt*16 + frow) = sv;
        }
    }
    // no barrier: t1 rows rb..rb+15 are wave-private (per-wave DS in-order)

    float4v acc2[6];
    #pragma unroll
    for (int n=0;n<6;n++) acc2[n] = fzero;

    const short8* w2f = (const short8*)w2sw;
    #pragma unroll
    for (int ks = 0; ks < 3; ++ks) {
        short8 bb = *(const short8*)(t1S + (rb+col)*104 + ks*32 + koff);
        #pragma unroll
        for (int mt = 0; mt < 6; ++mt) {
            short8 a = w2f[(ks*6+mt)*64 + lane];
            acc2[mt] = __builtin_amdgcn_mfma_f32_16x16x32_bf16(a, bb, acc2[mt], 0, 0, 0);
        }
    }
    float4v b2v[6];
    #pragma unroll
    for (int mt=0; mt<6; ++mt) b2v[mt] = *(const float4v*)(b2 + mt*16 + frow);
    // no barrier: new-h overwrites own wave's t1 rows (already consumed by own GEMM2)

    {
        int erow = rb + col;
        int node = n0 + erow;
        bool valid = node < N;
        size_t base = (size_t)node*HDIM;
        #pragma unroll
        for (int mt=0; mt<6; ++mt){
            int f0 = mt*16 + frow;
            float4v o;
            #pragma unroll
            for (int r=0;r<4;r++) o[r] = acc2[mt][r] + b2v[mt][r];
            short4v sv = {f2bf(o[0]), f2bf(o[1]), f2bf(o[2]), f2bf(o[3])};
            if (valid) *(short4v*)(hbf + base + f0) = sv;
            *(short4v*)(t1S + erow*104 + f0) = sv;
        }
    }
    // no barrier: SR reads own wave's rows

    // SR for layer 0
    float4v accS[12];
    #pragma unroll
    for (int n=0;n<12;n++) accS[n] = fzero;

    const short8* wsf = (const short8*)w1sr0;
    #pragma unroll
    for (int ks = 0; ks < 3; ++ks) {
        short8 bb = *(const short8*)(t1S + (rb+col)*104 + ks*32 + koff);
        #pragma unroll
        for (int mt = 0; mt < 12; ++mt) {
            short8 a = wsf[(ks*12+mt)*64 + lane];
            accS[mt] = __builtin_amdgcn_mfma_f32_16x16x32_bf16(a, bb, accS[mt], 0, 0, 0);
        }
    }
    float4v bnv[6];
    #pragma unroll
    for (int mt=0; mt<6; ++mt) bnv[mt] = *(const float4v*)(msgb1_0 + mt*16 + frow);

    {
        int node = n0 + rb + col;
        if (node < N) {
            size_t sbase = (size_t)node*192;
            #pragma unroll
            for (int mt=0; mt<12; ++mt){
                float4v o = accS[mt];
                if (mt < 6) { o[0]+=bnv[mt][0]; o[1]+=bnv[mt][1]; o[2]+=bnv[mt][2]; o[3]+=bnv[mt][3]; }
                short4v sv = {f2bf(o[0]), f2bf(o[1]), f2bf(o[2]), f2bf(o[3])};
                *(short4v*)(SR + sbase + mt*16 + frow) = sv;
            }
        }
    }
}

// ---------------- readout ----------------
__global__ __launch_bounds__(128) void readout_kernel(
    const float* __restrict__ pooled,
    const float* __restrict__ w1, const float* __restrict__ b1,
    const float* __restrict__ w2, const float* __restrict__ b2,
    float* __restrict__ out)
{
    __shared__ float red[128];
    const int g = blockIdx.x;
    const int t = threadIdx.x;
    float p = 0.0f;
    if (t < HDIM) {
        float acc = b1[t];
        for (int k = 0; k < HDIM; ++k)
            acc += pooled[(size_t)g*HDIM + k] * w1[(size_t)k*HDIM + t];
        acc = silu_f(acc);
        p = acc * w2[t];
    }
    red[t] = p;
    __syncthreads();
    for (int s = 64; s > 0; s >>= 1) {
        if (t < s) red[t] += red[t + s];
        __syncthreads();
    }
    if (t == 0) out[g] = red[0] + b2[0];
}

extern "C" void kernel_launch(void* const* d_in, const int* in_sizes, int n_in,
                              void* d_out, int out_size, void* d_ws, size_t ws_size,
                              hipStream_t stream)
{
    const float* x        = (const float*)d_in[0];
    const float* pos      = (const float*)d_in[1];
    const float* pe       = (const float*)d_in[2];
    const int*   ei       = (const int*)d_in[3];
    const int*   batch    = (const int*)d_in[4];
    const float* embed_w1 = (const float*)d_in[5];
    const float* embed_b1 = (const float*)d_in[6];
    const float* embed_w2 = (const float*)d_in[7];
    const float* embed_b2 = (const float*)d_in[8];
    const float* msg_w1   = (const float*)d_in[9];
    const float* msg_b1   = (const float*)d_in[10];
    const float* msg_w2   = (const float*)d_in[11];
    const float* msg_b2   = (const float*)d_in[12];
    const float* upd_w1   = (const float*)d_in[13];
    const float* upd_b1   = (const float*)d_in[14];
    const float* upd_w2   = (const float*)d_in[15];
    const float* upd_b2   = (const float*)d_in[16];
    const float* pre_w1   = (const float*)d_in[17];
    const float* pre_b1   = (const float*)d_in[18];
    const float* pre_w2   = (const float*)d_in[19];
    const float* pre_b2   = (const float*)d_in[20];
    const float* ro_w1    = (const float*)d_in[21];
    const float* ro_b1    = (const float*)d_in[22];
    const float* ro_w2    = (const float*)d_in[23];
    const float* ro_b2    = (const float*)d_in[24];

    const int E = in_sizes[3] / 2;
    const int N = in_sizes[4];
    const int G = out_size;

    char* ws = (char*)d_ws;
    size_t off = 0;
    auto alloc = [&](size_t bytes){ void* p = ws + off; off += (bytes + 255) & ~(size_t)255; return p; };
    short* hbf    = (short*)alloc((size_t)N*HDIM*2);
    float* aggr   = (float*)alloc((size_t)N*HDIM*4);
    float* stageA = (float*)alloc((size_t)N*HDIM*4);
    float* stageB = (float*)alloc((size_t)N*HDIM*4);
    float* pooled = (float*)alloc((size_t)G*HDIM*4);
    short* wsw    = (short*)alloc((size_t)59*3072*2);
    short* w1sr   = (short*)alloc((size_t)4*18432*2);
    short* SR     = (short*)alloc((size_t)N*192*2);
    int*   deg    = (int*)alloc((size_t)N*4);
    int*   cur    = (int*)alloc((size_t)N*4);
    int*   part   = (int*)alloc((size_t)256*4);
    int2*  sd_s   = (int2*)alloc((size_t)E*8);
    int*   rec_s  = (int*)alloc((size_t)E*4);

    hipMemsetAsync(deg, 0, (size_t)N*4, stream);   // must precede swizzle_all (hist phase)

    SwTable T;
    for (int jj=0;jj<22;jj++){ T.j[jj].src = embed_w1; T.j[jj].ck = 1<<30; T.j[jj].ks = 0; T.j[jj].ksrc = 0; }
    int ck = 0, ji = 0;
    auto add = [&](const float* s, int ks, int ksrc){
        T.j[ji].src = s; T.j[ji].ck = ck; T.j[ji].ks = ks; T.j[ji].ksrc = ksrc;
        ji++; ck += ks;
    };
    add(embed_w1, 2, 35);   // ck 0
    add(embed_w2, 3, 96);   // ck 2
    add(pre_w1,   3, 96);   // ck 5
    add(pre_w2,   3, 96);   // ck 8
    for (int l=0;l<4;l++) add(msg_w2 + (size_t)l*96*96,  3, 96);   // ck 11+3l
    for (int l=0;l<4;l++) add(upd_w1 + (size_t)l*192*96, 6, 192);  // ck 23+6l
    for (int l=0;l<4;l++) add(upd_w2 + (size_t)l*96*96,  3, 96);   // ck 47+3l
    const int total1 = 59*3072;
    const int total2 = 4*18432;
    const int nA = N*24;           // aggr float4s
    const int nP = G*24;           // pooled float4s
    const int totalAll = total1 + total2 + nA + nP + E;
    swizzle_all<<<(totalAll+255)/256, 256, 0, stream>>>(T, msg_w1, wsw, w1sr, total1, total2,
                                                       aggr, pooled, nA, nP, ei + E, deg, E);

    const int nbE256 = (E + 255) / 256;
    const int nbScan = (N + 1023) / 1024;
    scan_part<<<nbScan, 256, 0, stream>>>(deg, part, N);
    scan_top<<<1, 256, 0, stream>>>(part, nbScan);
    scan_final<<<nbScan, 256, 0, stream>>>(deg, part, cur, N);
    scatter_kernel<<<nbE256, 256, 0, stream>>>(ei, ei + E, pos, cur, sd_s, rec_s, E);

    const int nbN = (N + NTILE - 1) / NTILE;
    embed_kernel<<<nbN, 256, 0, stream>>>(x, pe, wsw + 0, embed_b1, wsw + 2*3072, embed_b2,
                                          hbf, w1sr, msg_b1, SR, N);

    const int nbE = (E + TILE - 1) / TILE;
    for (int l = 0; l < 4; ++l) {
        edge_kernel<<<nbE, 256, 0, stream>>>(SR, sd_s, rec_s,
            msg_w1 + (size_t)l*193*96 + (size_t)192*96,
            wsw + (11 + 3*l)*3072, msg_b2 + l*96, aggr, stageA, stageB, E);
        const short* w1sr_next  = (l < 3) ? (w1sr + (size_t)(l+1)*18432) : nullptr;
        const float* msgb1_next = (l < 3) ? (msg_b1 + (l+1)*96) : nullptr;
        const short* pw1 = (l == 3) ? (wsw + 5*3072) : nullptr;
        const float* pb1 = (l == 3) ? pre_b1 : nullptr;
        const short* pw2 = (l == 3) ? (wsw + 8*3072) : nullptr;
        const float* pb2 = (l == 3) ? pre_b2 : nullptr;
        update_kernel<<<nbN, 256, 0, stream>>>(hbf, aggr, stageA, stageB, deg,
            wsw + (23 + 6*l)*3072, upd_b1 + l*96,
            wsw + (47 + 3*l)*3072, upd_b2 + l*96,
            w1sr_next, msgb1_next, SR,
            pw1, pb1, pw2, pb2, batch, pooled, N);
    }

    readout_kernel<<<G, 128, 0, stream>>>(pooled, ro_w1, ro_b1, ro_w2, ro_b2, (float*)d_out);
}

// Round 13
// 672.828 us; speedup vs baseline: 1.0934x; 1.0511x over previous
//
#include <hip/hip_runtime.h>
#include <hip/hip_bf16.h>

#define HDIM 96
#define TILE 128
#define NTILE 64

typedef __attribute__((ext_vector_type(8))) short  short8;
typedef __attribute__((ext_vector_type(4))) short  short4v;
typedef __attribute__((ext_vector_type(4))) float  float4v;
typedef __attribute__((ext_vector_type(2))) float  float2v;
typedef __attribute__((ext_vector_type(4))) unsigned int uint4v;
typedef __attribute__((ext_vector_type(2))) unsigned int uint2v;

// fast bf16 round (round-half-away): 2 VALU inst vs ~5 for full RNE.
static __device__ __forceinline__ short f2bf(float f){
    unsigned u = __float_as_uint(f);
    return (short)((u + 0x8000u) >> 16);
}
static __device__ __forceinline__ float bf2f(short s){
    unsigned u = ((unsigned)(unsigned short)s) << 16;
    return __uint_as_float(u);
}
// fast silu: v * rcp(1+exp(-v)) — v_rcp_f32 is ~1ulp, fine at bf16 tolerance
static __device__ __forceinline__ float silu_f(float v){
    return v * __builtin_amdgcn_rcpf(1.0f + __expf(-v));
}
// packed-pair silu -> packed bf16 u32 (elem0 low 16, elem1 high 16); v_pk_* friendly.
static __device__ __forceinline__ unsigned silu2_pack(float2v v){
    float e0 = __expf(-v[0]);
    float e1 = __expf(-v[1]);
    float2v ep = {e0, e1};
    const float2v one2 = {1.0f, 1.0f};
    ep += one2;
    float2v q = { __builtin_amdgcn_rcpf(ep[0]), __builtin_amdgcn_rcpf(ep[1]) };
    float2v res = v * q;
    unsigned pa = __float_as_uint(res[0]) + 0x8000u;
    unsigned pb = __float_as_uint(res[1]) + 0x8000u;
    return __builtin_amdgcn_perm(pb, pa, 0x07060302);
}

// async global->LDS, 16B per lane, per-lane GLOBAL src, wave-uniform LDS base (+lane*16 in HW)
typedef __attribute__((address_space(1))) const unsigned int guint;
typedef __attribute__((address_space(3))) unsigned int luint;
static __device__ __forceinline__ void gload_lds16(const void* g, void* l){
    __builtin_amdgcn_global_load_lds((guint*)g, (luint*)l, 16, 0, 0);
}

// ---------------- weight swizzle + workspace zeroing + edge histogram (merged) ----------------
// hist phase is safe here because deg is zeroed by a hipMemsetAsync that PRECEDES
// this kernel in stream order.
struct SwJob { const float* src; int ck; int ks; int ksrc; };
struct SwTable { SwJob j[22]; };

__global__ __launch_bounds__(256) void swizzle_all(SwTable T, const float* __restrict__ msg_w1,
                                                   short* __restrict__ dst, short* __restrict__ dst2,
                                                   int total1, int total2,
                                                   float* __restrict__ aggrZ, float* __restrict__ pooledZ,
                                                   int nA, int nP,
                                                   const int* __restrict__ recH, int* __restrict__ deg, int E){
    int gid = blockIdx.x*256 + threadIdx.x;
    if (gid < total1) {
        int ksg = gid / 3072;
        int e   = gid % 3072;
        const float* src = T.j[0].src; int k0 = 0, ksrc = 0;
        #pragma unroll
        for (int jj = 0; jj < 22; ++jj){
            int s = T.j[jj].ck;
            if (ksg >= s && ksg < s + T.j[jj].ks){ src = T.j[jj].src; k0 = (ksg - s)*32; ksrc = T.j[jj].ksrc; }
        }
        int nt   = e >> 9;
        int rem  = e & 511;
        int lane = rem >> 3;
        int jx   = rem & 7;
        int k = k0 + ((lane >> 4) << 3) + jx;
        int f = nt*16 + (lane & 15);
        float v = (k < ksrc) ? src[(size_t)k*HDIM + f] : 0.0f;
        dst[gid] = f2bf(v);
    } else if (gid < total1 + total2) {
        int g2 = gid - total1;
        int layer = g2 / 18432;
        int e     = g2 % 18432;
        int ksg = e / 6144;
        int rem = e % 6144;
        int nt   = rem >> 9;
        int r2   = rem & 511;
        int lane = r2 >> 3;
        int jx   = r2 & 7;
        int k = ksg*32 + ((lane >> 4) << 3) + jx;     // 0..95
        int f = nt*16 + (lane & 15);                  // 0..191
        int row = (f < 96) ? k : (96 + k);
        int col = (f < 96) ? f : (f - 96);
        dst2[g2] = f2bf(msg_w1[(size_t)layer*193*96 + (size_t)row*96 + col]);
    } else if (gid < total1 + total2 + nA + nP) {
        int gz = gid - total1 - total2;
        const float4v z = {0.f,0.f,0.f,0.f};
        if (gz < nA)  ((float4v*)aggrZ)[gz] = z;
        else          ((float4v*)pooledZ)[gz - nA] = z;
    } else {
        int e = gid - total1 - total2 - nA - nP;
        if (e < E) atomicAdd(&deg[recH[e]], 1);
    }
}

// ---------------- edge sorting scans (counting sort by rec) ----------------
__global__ __launch_bounds__(256) void scan_part(const int* __restrict__ deg, int* __restrict__ part, int N){
    __shared__ int red[256];
    const int t = threadIdx.x;
    int base = blockIdx.x*1024;
    int s = 0;
    #pragma unroll
    for (int j=0;j<4;j++){ int i = base + j*256 + t; s += (i<N)?deg[i]:0; }
    red[t]=s; __syncthreads();
    #pragma unroll
    for (int off=128; off>0; off>>=1){ if (t<off) red[t]+=red[t+off]; __syncthreads(); }
    if (t==0) part[blockIdx.x]=red[0];
}
__global__ __launch_bounds__(256) void scan_top(int* __restrict__ part, int nb){
    __shared__ int buf[256];
    const int t = threadIdx.x;
    int v = (t < nb) ? part[t] : 0;
    buf[t] = v;
    __syncthreads();
    #pragma unroll
    for (int off=1; off<256; off<<=1){
        int u = (t>=off)?buf[t-off]:0;
        __syncthreads();
        buf[t] += u;
        __syncthreads();
    }
    if (t < nb) part[t] = buf[t] - v;
}
// scan_final also precomputes the per-node tile-boundary flag and packs it into deg's sign bit.
__global__ __launch_bounds__(256) void scan_final(int* __restrict__ deg, const int* __restrict__ part,
                                                  int* __restrict__ cur, int N){
    __shared__ int tsum[256];
    const int t = threadIdx.x;
    int i0 = blockIdx.x*1024 + t*4;
    int a0 = (i0+0<N)?deg[i0+0]:0;
    int a1 = (i0+1<N)?deg[i0+1]:0;
    int a2 = (i0+2<N)?deg[i0+2]:0;
    int a3 = (i0+3<N)?deg[i0+3]:0;
    int s = a0+a1+a2+a3;
    tsum[t]=s; __syncthreads();
    #pragma unroll
    for (int off=1; off<256; off<<=1){
        int u = (t>=off)?tsum[t-off]:0;
        __syncthreads();
        tsum[t]+=u;
        __syncthreads();
    }
    int excl = tsum[t]-s + part[blockIdx.x];
    int e0 = excl, e1 = excl+a0, e2 = excl+a0+a1, e3 = excl+a0+a1+a2;
    if (i0+0<N){ cur[i0+0]=e0; if (a0>0 && (e0>>7)!=((e0+a0-1)>>7)) deg[i0+0]=a0|0x80000000; }
    if (i0+1<N){ cur[i0+1]=e1; if (a1>0 && (e1>>7)!=((e1+a1-1)>>7)) deg[i0+1]=a1|0x80000000; }
    if (i0+2<N){ cur[i0+2]=e2; if (a2>0 && (e2>>7)!=((e2+a2-1)>>7)) deg[i0+2]=a2|0x80000000; }
    if (i0+3<N){ cur[i0+3]=e3; if (a3>0 && (e3>>7)!=((e3+a3-1)>>7)) deg[i0+3]=a3|0x80000000; }
}

__global__ __launch_bounds__(256) void scatter_kernel(
    const int* __restrict__ send, const int* __restrict__ rec, const float* __restrict__ pos,
    int* __restrict__ cur, int2* __restrict__ sd_s, int* __restrict__ rec_s, int E)
{
    int e = blockIdx.x*256 + threadIdx.x;
    if (e >= E) return;
    int s = send[e], r = rec[e];
    int p = atomicAdd(&cur[r], 1);
    float dx = pos[3*s]   - pos[3*r];
    float dy = pos[3*s+1] - pos[3*r+1];
    float dz = pos[3*s+2] - pos[3*r+2];
    float d = sqrtf(dx*dx + dy*dy + dz*dz);
    sd_s[p] = make_int2(s, __float_as_int(d));
    rec_s[p] = r;
    // after this kernel: cur[r] = end offset of node r's run; deg[r] = run length | bndflag
}

// ---------------- edge: gather SR, silu into B-frags, GEMM2, segment-reduce ----------------
// R13: champion config restored — 4-wave/256-thread/5-block, chunk-major gload_lds
// staging, NO setprio (R12's isolated A/B: setprio alone cost +6.5us with WRITE
// 21->83MB / FETCH 87->100MB; priority skew breaks cross-wave temporal write
// coalescing under L2 pressure -> partial-line eviction + re-fetch). Occupancy
// ledger: more blocks = L2 thrash (R1); more waves/block = overhead (R11);
// this config is the defended local optimum at ~87.5us.
template<bool FULL>
static __device__ __forceinline__ void edge_body(
    const short* __restrict__ SR,
    const int2* __restrict__ sd_s, const int* __restrict__ rec_s,
    const float* __restrict__ w1r192,
    const short* __restrict__ w2sw, const float* __restrict__ b2,
    float* __restrict__ aggr, float* __restrict__ stageA, float* __restrict__ stageB, int E,
    short* msgS, int* recS, int* startIdxS, int* wcntS)
{
    const int t  = threadIdx.x;
    const int e0 = blockIdx.x * TILE;
    const int lane = t & 63;
    const int wv   = t >> 6;
    const int e_lo = wv * 32;
    const int col  = lane & 15;
    const int quad = lane >> 4;
    const int frow = quad * 4;
    const float4v fzero = {0.f,0.f,0.f,0.f};
    const int emax = E - 1;

    // ---- S-side staging: 24 wave-instrs, chunk-major [cc][e] layout ----
    int seStage[6];
    const int* sdp = (const int*)sd_s;
    #pragma unroll
    for (int i=0;i<6;i++){
        int idx = i*4 + wv;
        int e  = ((idx & 1) << 6) + lane;
        int ec = e0 + e;
        if (!FULL) ec = min(ec, emax);
        seStage[i] = sdp[2*ec];
    }
    #pragma unroll
    for (int i=0;i<6;i++){
        int idx = i*4 + wv;
        int cc  = idx >> 1;
        const short* src = SR + (size_t)seStage[i]*192 + cc*8;
        gload_lds16(src, msgS + idx*512);   // LDS byte base idx*1024, +lane*16
    }

    // ---- own-edge metadata + cache-hot rec-side gathers (registers) ----
    int re[2]; float dd[2];
    #pragma unroll
    for (int et=0; et<2; ++et){
        int ec = e0 + e_lo + et*16 + col;
        if (!FULL) ec = min(ec, emax);
        int2 sd = sd_s[ec];
        dd[et] = __int_as_float(sd.y);
        re[et] = rec_s[ec];
    }
    uint4v Rvu[2][3];
    #pragma unroll
    for (int et=0; et<2; ++et)
      #pragma unroll
      for (int ks=0; ks<3; ++ks){
        int f0 = ks*32 + quad*8;
        Rvu[et][ks] = *(const uint4v*)(SR + (size_t)re[et]*192 + 96 + f0);
      }

    // ---- segment table from global reads ----
    int myRec = 0;
    bool flag = false;
    if (t < TILE) {
        int e = e0 + t;
        if (!FULL) e = min(e, emax);
        myRec = rec_s[e];
        recS[t] = myRec;
        int ep = e0 + t - 1;
        if (!FULL && ep > emax) ep = emax;
        flag = (t == 0) || (myRec != rec_s[ep]);
    }
    unsigned long long bmask = __ballot(flag ? 1 : 0);
    int pre = __popcll(bmask & ((1ull << (t & 63)) - 1ull));
    if (t < TILE && (t & 63) == 0) wcntS[t >> 6] = __popcll(bmask);

    const bool firstB = (e0 > 0) && (rec_s[e0-1] == rec_s[e0]);
    const bool lastB  = (e0 + TILE < E) && (rec_s[e0 + TILE] == rec_s[FULL ? (e0+TILE-1) : min(e0+TILE-1, emax)]);

    __syncthreads();   // staging drained (vmcnt0) + recS/wcntS visible

    if (flag) startIdxS[pre + ((t >> 6) ? wcntS[0] : 0)] = t;
    if (t == 0) startIdxS[wcntS[0] + wcntS[1]] = TILE;

    // ---- build B-fragments: S from LDS staging (chunk-major), R from registers ----
    short8 frag[2][3];
    #pragma unroll
    for (int et=0; et<2; ++et){
        float2v d2 = {dd[et], dd[et]};
        int e_local = e_lo + et*16 + col;
        #pragma unroll
        for (int ks=0; ks<3; ++ks){
            int f0 = ks*32 + quad*8;
            const float2v* wp = (const float2v*)(w1r192 + f0);
            uint4v su = *(const uint4v*)(msgS + (ks*4+quad)*1024 + e_local*8);
            uint4v ru = Rvu[et][ks];
            uint4v fo;
            #pragma unroll
            for (int p=0;p<4;p++){
                float2v w2 = wp[p];
                unsigned us = su[p], ur = ru[p];
                float2v s2 = { __uint_as_float(us << 16), __uint_as_float(us & 0xffff0000u) };
                float2v r2 = { __uint_as_float(ur << 16), __uint_as_float(ur & 0xffff0000u) };
                float2v v = s2 + r2 + d2*w2;
                fo[p] = silu2_pack(v);
            }
            short8 fr;
            __builtin_memcpy(&fr, &fo, 16);
            frag[et][ks] = fr;
        }
    }
    __syncthreads();   // all S ds_reads done before epilogue overwrites msgS

    float4v acc2[2][6];
    #pragma unroll
    for (int i=0;i<2;i++)
      #pragma unroll
      for (int n=0;n<6;n++) acc2[i][n] = fzero;

    const short8* w2f = (const short8*)w2sw;
    #pragma unroll
    for (int ks = 0; ks < 3; ++ks) {
        #pragma unroll
        for (int mt = 0; mt < 6; ++mt) {
            short8 a = w2f[(ks*6+mt)*64 + lane];
            acc2[0][mt] = __builtin_amdgcn_mfma_f32_16x16x32_bf16(a, frag[0][ks], acc2[0][mt], 0, 0, 0);
            acc2[1][mt] = __builtin_amdgcn_mfma_f32_16x16x32_bf16(a, frag[1][ks], acc2[1][mt], 0, 0, 0);
        }
    }
    float4v b2v[6];
    #pragma unroll
    for (int mt=0; mt<6; ++mt) b2v[mt] = *(const float4v*)(b2 + mt*16 + frow);

    #pragma unroll
    for (int et=0; et<2; ++et){
        int e = e_lo + et*16 + col;
        bool valid = FULL || ((e0 + e) < E);
        #pragma unroll
        for (int mt=0; mt<6; ++mt){
            float2v aLo = *(const float2v*)&acc2[et][mt];
            float2v aHi = *((const float2v*)&acc2[et][mt] + 1);
            float2v bLo = *(const float2v*)&b2v[mt];
            float2v bHi = *((const float2v*)&b2v[mt] + 1);
            unsigned ulo = silu2_pack(aLo + bLo);
            unsigned uhi = silu2_pack(aHi + bHi);
            if (!valid){ ulo = 0u; uhi = 0u; }
            uint2v st = {ulo, uhi};
            *(uint2v*)(msgS + e*104 + mt*16 + frow) = st;
        }
    }
    __syncthreads();

    // segment-sum: 4-col items (nseg*24); packed-pair unpack + pk accumulate
    const int nseg = wcntS[0] + wcntS[1];
    const int items = nseg * 24;
    for (int item = t; item < items; item += 256){
        int s  = item / 24;
        int fg = item - s*24;
        int r0 = startIdxS[s], r1 = startIdxS[s+1];
        float2v s01 = {0.f,0.f}, s23 = {0.f,0.f};
        for (int r = r0; r < r1; ++r){
            const unsigned* pp = (const unsigned*)(msgS + r*104 + fg*4);
            unsigned p0 = pp[0], p1 = pp[1];
            float2v a0 = { __uint_as_float(p0 << 16), __uint_as_float(p0 & 0xffff0000u) };
            float2v a1 = { __uint_as_float(p1 << 16), __uint_as_float(p1 & 0xffff0000u) };
            s01 += a0; s23 += a1;
        }
        int node = recS[r0];
        float* dstp;
        if (s == 0 && firstB)            dstp = stageB + (size_t)node*HDIM + fg*4;  // head partial
        else if (s == nseg-1 && lastB)   dstp = stageA + (size_t)node*HDIM + fg*4;  // tail partial
        else                             dstp = aggr   + (size_t)node*HDIM + fg*4;  // complete row
        float4v v = {s01[0], s01[1], s23[0], s23[1]};
        *(float4v*)(dstp) = v;
    }
}

__global__ __launch_bounds__(256,5) void edge_kernel(
    const short* __restrict__ SR,
    const int2* __restrict__ sd_s, const int* __restrict__ rec_s,
    const float* __restrict__ w1r192,
    const short* __restrict__ w2sw, const float* __restrict__ b2,
    float* __restrict__ aggr, float* __restrict__ stageA, float* __restrict__ stageB, int E)
{
    __shared__ short msgS[TILE*104];     // phase A: S-staging (24576 B used); phase B: msg (26624 B)
    __shared__ int   recS[TILE];
    __shared__ int   startIdxS[TILE+1];
    __shared__ int   wcntS[2];
    const int e0 = blockIdx.x * TILE;
    if (e0 + TILE <= E)
        edge_body<true >(SR, sd_s, rec_s, w1r192, w2sw, b2, aggr, stageA, stageB, E, msgS, recS, startIdxS, wcntS);
    else
        edge_body<false>(SR, sd_s, rec_s, w1r192, w2sw, b2, aggr, stageA, stageB, E, msgS, recS, startIdxS, wcntS);
}

// ---------------- node update: hbf += MLP([h,aggr]) (bf16 residual); SR tail or prepool tail ----------------
// Zero-barrier, zero-staging main path (R9): all LDS producer->consumer pairs are
// intra-wave; GEMM1 B-fragments load directly from global.
__global__ __launch_bounds__(256,3) void update_kernel(
    short* __restrict__ hbf, const float* __restrict__ aggr,
    const float* __restrict__ stageA, const float* __restrict__ stageB,
    const int* __restrict__ deg,
    const short* __restrict__ w1sw, const float* __restrict__ b1,
    const short* __restrict__ w2sw, const float* __restrict__ b2,
    const short* __restrict__ w1sr_next, const float* __restrict__ msgb1_next,
    short* __restrict__ SR,
    const short* __restrict__ pw1, const float* __restrict__ pb1,
    const short* __restrict__ pw2, const float* __restrict__ pb2,
    const int* __restrict__ batch, float* __restrict__ pooled, int N)
{
    __shared__ short stateS[NTILE*208];   // region0=[0,6656) region1=[6656,13312) shorts
    __shared__ int   batchS[NTILE];
    __shared__ int   startIdxS[NTILE+1];
    __shared__ int   nsegS;
    const int t  = threadIdx.x;
    const int n0 = blockIdx.x * NTILE;
    const int lane = t & 63;
    const int wv   = t >> 6;        // 0..3
    const int rb   = wv * 16;       // wave's row base
    const int col  = lane & 15;
    const int quad = lane >> 4;
    const int koff = quad * 8;
    const int frow = quad * 4;
    const float4v fzero = {0.f,0.f,0.f,0.f};

    const int nodeRaw = n0 + rb + col;
    const bool valid  = nodeRaw < N;
    const int  node   = valid ? nodeRaw : N - 1;
    const size_t hbase = (size_t)node * HDIM;

    // ---- direct B-fragments (no LDS staging, no barrier) ----
    short8 bh[3];
    #pragma unroll
    for (int ks=0; ks<3; ++ks)
        bh[ks] = *(const short8*)(hbf + hbase + ks*32 + koff);

    const bool bnd = deg[node] < 0;    // precomputed tile-boundary flag
    short8 ba[3];
    #pragma unroll
    for (int ks=0; ks<3; ++ks){
        size_t b = hbase + ks*32 + koff;
        float4v a0, a1;
        if (bnd){
            a0 = *(const float4v*)(stageA + b)     + *(const float4v*)(stageB + b);
            a1 = *(const float4v*)(stageA + b + 4) + *(const float4v*)(stageB + b + 4);
        } else {
            a0 = *(const float4v*)(aggr + b);
            a1 = *(const float4v*)(aggr + b + 4);
        }
        short8 s8;
        s8[0]=f2bf(a0[0]); s8[1]=f2bf(a0[1]); s8[2]=f2bf(a0[2]); s8[3]=f2bf(a0[3]);
        s8[4]=f2bf(a1[0]); s8[5]=f2bf(a1[1]); s8[6]=f2bf(a1[2]); s8[7]=f2bf(a1[3]);
        ba[ks] = s8;
    }

    float4v acc[6];
    #pragma unroll
    for (int n=0;n<6;n++) acc[n] = fzero;

    const short8* w1f = (const short8*)w1sw;
    #pragma unroll
    for (int ks = 0; ks < 6; ++ks) {
        short8 bb = (ks < 3) ? bh[ks] : ba[ks-3];
        #pragma unroll
        for (int mt = 0; mt < 6; ++mt) {
            short8 a = w1f[(ks*6+mt)*64 + lane];
            acc[mt] = __builtin_amdgcn_mfma_f32_16x16x32_bf16(a, bb, acc[mt], 0, 0, 0);
        }
    }
    float4v b1v[6];
    #pragma unroll
    for (int mt=0; mt<6; ++mt) b1v[mt] = *(const float4v*)(b1 + mt*16 + frow);

    short* t1S = stateS;   // stride 104, region0; wave-private rows rb..rb+15
    {
        int e = rb + col;
        #pragma unroll
        for (int mt=0; mt<6; ++mt){
            short4v sv;
            #pragma unroll
            for (int r=0;r<4;r++) sv[r] = f2bf(silu_f(acc[mt][r] + b1v[mt][r]));
            *(short4v*)(t1S + e*104 + mt*16 + frow) = sv;
        }
    }
    // no barrier: GEMM2 reads only this wave's rows (per-wave DS in-order)

    float4v acc2[6];
    #pragma unroll
    for (int n=0;n<6;n++) acc2[n] = fzero;

    const short8* w2f = (const short8*)w2sw;
    #pragma unroll
    for (int ks = 0; ks < 3; ++ks) {
        short8 bb = *(const short8*)(t1S + (rb+col)*104 + ks*32 + koff);
        #pragma unroll
        for (int mt = 0; mt < 6; ++mt) {
            short8 a = w2f[(ks*6+mt)*64 + lane];
            acc2[mt] = __builtin_amdgcn_mfma_f32_16x16x32_bf16(a, bb, acc2[mt], 0, 0, 0);
        }
    }
    float4v b2v[6];
    #pragma unroll
    for (int mt=0; mt<6; ++mt) b2v[mt] = *(const float4v*)(b2 + mt*16 + frow);

    {
        int erow = rb + col;
        size_t base = (size_t)node*HDIM;
        #pragma unroll
        for (int mt=0; mt<6; ++mt){
            int f0 = mt*16 + frow;
            short4v ov = {0,0,0,0};
            if (valid) ov = *(const short4v*)(hbf + base + f0);
            float4v o;
            #pragma unroll
            for (int r=0;r<4;r++) o[r] = bf2f(ov[r]) + acc2[mt][r] + b2v[mt][r];
            short4v sv = {f2bf(o[0]), f2bf(o[1]), f2bf(o[2]), f2bf(o[3])};
            if (valid) *(short4v*)(hbf + base + f0) = sv;
            *(short4v*)(stateS + erow*104 + f0) = sv;   // new h (overwrites own t1 rows, already consumed)
        }
    }

    if (w1sr_next) {   // SR tail for next layer (l<3): intra-wave reads, no barrier
        float4v accS[12];
        #pragma unroll
        for (int n=0;n<12;n++) accS[n] = fzero;

        const short8* wsf = (const short8*)w1sr_next;
        #pragma unroll
        for (int ks = 0; ks < 3; ++ks) {
            short8 bb = *(const short8*)(stateS + (rb+col)*104 + ks*32 + koff);
            #pragma unroll
            for (int mt = 0; mt < 12; ++mt) {
                short8 a = wsf[(ks*12+mt)*64 + lane];
                accS[mt] = __builtin_amdgcn_mfma_f32_16x16x32_bf16(a, bb, accS[mt], 0, 0, 0);
            }
        }
        float4v bnv[6];
        #pragma unroll
        for (int mt=0; mt<6; ++mt) bnv[mt] = *(const float4v*)(msgb1_next + mt*16 + frow);

        if (valid) {
            size_t sbase = (size_t)node*192;
            #pragma unroll
            for (int mt=0; mt<12; ++mt){
                float4v o = accS[mt];
                if (mt < 6) { o[0]+=bnv[mt][0]; o[1]+=bnv[mt][1]; o[2]+=bnv[mt][2]; o[3]+=bnv[mt][3]; }
                short4v sv = {f2bf(o[0]), f2bf(o[1]), f2bf(o[2]), f2bf(o[3])};
                *(short4v*)(SR + sbase + mt*16 + frow) = sv;
            }
        }
    } else if (pw1) {   // fused pre-MLP + pooling tail (l=3): keeps cross-wave barriers
        if (t < NTILE) {
            int nd = n0 + t;
            batchS[t] = batch[nd < N ? nd : N-1];
        }
        __syncthreads();   // batchS visible

        bool flag = false;
        if (t < NTILE) flag = (t == 0) || (batchS[t] != batchS[t-1]);
        unsigned long long bm = __ballot(flag ? 1 : 0);
        if (t < NTILE) {
            int pre = __popcll(bm & ((1ull << t) - 1ull));
            if (flag) startIdxS[pre] = t;
            if (t == 0) nsegS = __popcll(bm);
        }

        float4v accp[6];
        #pragma unroll
        for (int n=0;n<6;n++) accp[n] = fzero;

        const short8* pw1f = (const short8*)pw1;
        #pragma unroll
        for (int ks = 0; ks < 3; ++ks) {
            short8 bb = *(const short8*)(stateS + (rb+col)*104 + ks*32 + koff);
            #pragma unroll
            for (int mt = 0; mt < 6; ++mt) {
                short8 a = pw1f[(ks*6+mt)*64 + lane];
                accp[mt] = __builtin_amdgcn_mfma_f32_16x16x32_bf16(a, bb, accp[mt], 0, 0, 0);
            }
        }
        float4v pb1v[6];
        #pragma unroll
        for (int mt=0; mt<6; ++mt) pb1v[mt] = *(const float4v*)(pb1 + mt*16 + frow);

        short* t1p = stateS + NTILE*104;   // region1; wave-private rows
        {
            int e = rb + col;
            #pragma unroll
            for (int mt=0; mt<6; ++mt){
                short4v sv;
                #pragma unroll
                for (int r=0;r<4;r++) sv[r] = f2bf(silu_f(accp[mt][r] + pb1v[mt][r]));
                *(short4v*)(t1p + e*104 + mt*16 + frow) = sv;
            }
        }

        float4v accq[6];
        #pragma unroll
        for (int n=0;n<6;n++) accq[n] = fzero;

        const short8* pw2f = (const short8*)pw2;
        #pragma unroll
        for (int ks = 0; ks < 3; ++ks) {
            short8 bb = *(const short8*)(t1p + (rb+col)*104 + ks*32 + koff);
            #pragma unroll
            for (int mt = 0; mt < 6; ++mt) {
                short8 a = pw2f[(ks*6+mt)*64 + lane];
                accq[mt] = __builtin_amdgcn_mfma_f32_16x16x32_bf16(a, bb, accq[mt], 0, 0, 0);
            }
        }
        float4v pb2v[6];
        #pragma unroll
        for (int mt=0; mt<6; ++mt) pb2v[mt] = *(const float4v*)(pb2 + mt*16 + frow);
        __syncthreads();   // ALL waves done reading stateS/t1p; msgS overwrites both regions

        float* msgS = (float*)stateS;   // stride 100 floats, 25600 B
        {
            int e = rb + col;
            #pragma unroll
            for (int mt=0; mt<6; ++mt){
                float4v v;
                #pragma unroll
                for (int r=0;r<4;r++){
                    float u = accq[mt][r] + pb2v[mt][r];
                    v[r] = valid ? u : 0.0f;
                }
                *(float4v*)(msgS + e*100 + mt*16 + frow) = v;
            }
        }
        __syncthreads();

        const int nseg = nsegS;
        if (t == 0) startIdxS[nseg] = NTILE;
        __syncthreads();

        const int items = nseg * 24;
        for (int item = t; item < items; item += 256){
            int s  = item / 24;
            int fg = item - s*24;
            int r0 = startIdxS[s], r1 = startIdxS[s+1];
            float4v sum = fzero;
            for (int r = r0; r < r1; ++r) sum += *(const float4v*)(msgS + r*100 + fg*4);
            float* dstp = pooled + (size_t)batchS[r0]*HDIM + fg*4;
            atomicAdd(dstp+0, sum[0]);
            atomicAdd(dstp+1, sum[1]);
            atomicAdd(dstp+2, sum[2]);
            atomicAdd(dstp+3, sum[3]);
        }
    }
}

// ---------------- embed (NTILE=64, 256 threads) ----------------
// Parallel staging (all 256 threads) + single barrier; t1/new-h/SR phases are
// intra-wave -> no barriers.
__global__ __launch_bounds__(256,3) void embed_kernel(
    const float* __restrict__ x, const float* __restrict__ pe,
    const short* __restrict__ w1sw, const float* __restrict__ b1,
    const short* __restrict__ w2sw, const float* __restrict__ b2,
    short* __restrict__ hbf,
    const short* __restrict__ w1sr0, const float* __restrict__ msgb1_0,
    short* __restrict__ SR, int N)
{
    __shared__ short stateS[NTILE*72];    // 9216 B (k 0..63 used)
    __shared__ short t1S[NTILE*104];      // 13312 B
    const int t  = threadIdx.x;
    const int n0 = blockIdx.x * NTILE;

    // parallel staging: item = (row = t>>2, k0 = (t&3)*16); 256 items cover 64x4
    {
        int row  = t >> 2;
        int k0   = (t & 3) << 4;
        int nodeS = n0 + row;
        short tmp[16];
        if (nodeS < N && k0 < 48) {
            const float* xr  = x  + (size_t)nodeS*11;
            const float* per = pe + (size_t)nodeS*24;
            #pragma unroll
            for (int j=0;j<16;j++){
                int k = k0 + j;
                float v = 0.f;
                if (k < 11)      v = xr[k];
                else if (k < 35) v = per[k-11];
                tmp[j] = f2bf(v);
            }
        } else {
            #pragma unroll
            for (int j=0;j<16;j++) tmp[j] = 0;
        }
        #pragma unroll
        for (int j=0;j<4;j++)
            *(short4v*)(stateS + row*72 + k0 + j*4) = *(short4v*)&tmp[j*4];
    }
    __syncthreads();   // cross-wave staging -> the ONE barrier

    const int lane = t & 63;
    const int wv   = t >> 6;        // 0..3
    const int rb   = wv * 16;
    const int col  = lane & 15;
    const int quad = lane >> 4;
    const int koff = quad * 8;
    const int frow = quad * 4;
    const float4v fzero = {0.f,0.f,0.f,0.f};

    float4v acc[6];
    #pragma unroll
    for (int n=0;n<6;n++) acc[n] = fzero;

    const short8* w1f = (const short8*)w1sw;
    #pragma unroll
    for (int ks = 0; ks < 2; ++ks) {
        short8 bb = *(const short8*)(stateS + (rb+col)*72 + ks*32 + koff);
        #pragma unroll
        for (int mt = 0; mt < 6; ++mt) {
            short8 a = w1f[(ks*6+mt)*64 + lane];
            acc[mt] = __builtin_amdgcn_mfma_f32_16x16x32_bf16(a, bb, acc[mt], 0, 0, 0);
        }
    }
    float4v b1v[6];
    #pragma unroll
    for (int mt=0; mt<6; ++mt) b1v[mt] = *(const float4v*)(b1 + mt*16 + frow);

    {
        int e = rb + col;
        #pragma unroll
        for (int mt=0; mt<6; ++mt){
            short4v sv;
            #pragma unroll
            for (int r=0;r<4;r++) sv[r] = f2bf(silu_f(acc[mt][r] + b1v[mt][r]));
            *(short4v*)(t1S + e*104 + mt*16 + frow) = sv;
        }
    }
    // no barrier: t1 rows rb..rb+15 are wave-private (per-wave DS in-order)

    float4v acc2[6];
    #pragma unroll
    for (int n=0;n<6;n++) acc2[n] = fzero;

    const short8* w2f = (const short8*)w2sw;
    #pragma unroll
    for (int ks = 0; ks < 3; ++ks) {
        short8 bb = *(const short8*)(t1S + (rb+col)*104 + ks*32 + koff);
        #pragma unroll
        for (int mt = 0; mt < 6; ++mt) {
            short8 a = w2f[(ks*6+mt)*64 + lane];
            acc2[mt] = __builtin_amdgcn_mfma_f32_16x16x32_bf16(a, bb, acc2[mt], 0, 0, 0);
        }
    }
    float4v b2v[6];
    #pragma unroll
    for (int mt=0; mt<6; ++mt) b2v[mt] = *(const float4v*)(b2 + mt*16 + frow);
    // no barrier: new-h overwrites own wave's t1 rows (already consumed by own GEMM2)

    {
        int erow = rb + col;
        int node = n0 + erow;
        bool valid = node < N;
        size_t base = (size_t)node*HDIM;
        #pragma unroll
        for (int mt=0; mt<6; ++mt){
            int f0 = mt*16 + frow;
            float4v o;
            #pragma unroll
            for (int r=0;r<4;r++) o[r] = acc2[mt][r] + b2v[mt][r];
            short4v sv = {f2bf(o[0]), f2bf(o[1]), f2bf(o[2]), f2bf(o[3])};
            if (valid) *(short4v*)(hbf + base + f0) = sv;
            *(short4v*)(t1S + erow*104 + f0) = sv;
        }
    }
    // no barrier: SR reads own wave's rows

    // SR for layer 0
    float4v accS[12];
    #pragma unroll
    for (int n=0;n<12;n++) accS[n] = fzero;

    const short8* wsf = (const short8*)w1sr0;
    #pragma unroll
    for (int ks = 0; ks < 3; ++ks) {
        short8 bb = *(const short8*)(t1S + (rb+col)*104 + ks*32 + koff);
        #pragma unroll
        for (int mt = 0; mt < 12; ++mt) {
            short8 a = wsf[(ks*12+mt)*64 + lane];
            accS[mt] = __builtin_amdgcn_mfma_f32_16x16x32_bf16(a, bb, accS[mt], 0, 0, 0);
        }
    }
    float4v bnv[6];
    #pragma unroll
    for (int mt=0; mt<6; ++mt) bnv[mt] = *(const float4v*)(msgb1_0 + mt*16 + frow);

    {
        int node = n0 + rb + col;
        if (node < N) {
            size_t sbase = (size_t)node*192;
            #pragma unroll
            for (int mt=0; mt<12; ++mt){
                float4v o = accS[mt];
                if (mt < 6) { o[0]+=bnv[mt][0]; o[1]+=bnv[mt][1]; o[2]+=bnv[mt][2]; o[3]+=bnv[mt][3]; }
                short4v sv = {f2bf(o[0]), f2bf(o[1]), f2bf(o[2]), f2bf(o[3])};
                *(short4v*)(SR + sbase + mt*16 + frow) = sv;
            }
        }
    }
}

// ---------------- readout ----------------
__global__ __launch_bounds__(128) void readout_kernel(
    const float* __restrict__ pooled,
    const float* __restrict__ w1, const float* __restrict__ b1,
    const float* __restrict__ w2, const float* __restrict__ b2,
    float* __restrict__ out)
{
    __shared__ float red[128];
    const int g = blockIdx.x;
    const int t = threadIdx.x;
    float p = 0.0f;
    if (t < HDIM) {
        float acc = b1[t];
        for (int k = 0; k < HDIM; ++k)
            acc += pooled[(size_t)g*HDIM + k] * w1[(size_t)k*HDIM + t];
        acc = silu_f(acc);
        p = acc * w2[t];
    }
    red[t] = p;
    __syncthreads();
    for (int s = 64; s > 0; s >>= 1) {
        if (t < s) red[t] += red[t + s];
        __syncthreads();
    }
    if (t == 0) out[g] = red[0] + b2[0];
}

extern "C" void kernel_launch(void* const* d_in, const int* in_sizes, int n_in,
                              void* d_out, int out_size, void* d_ws, size_t ws_size,
                              hipStream_t stream)
{
    const float* x        = (const float*)d_in[0];
    const float* pos      = (const float*)d_in[1];
    const float* pe       = (const float*)d_in[2];
    const int*   ei       = (const int*)d_in[3];
    const int*   batch    = (const int*)d_in[4];
    const float* embed_w1 = (const float*)d_in[5];
    const float* embed_b1 = (const float*)d_in[6];
    const float* embed_w2 = (const float*)d_in[7];
    const float* embed_b2 = (const float*)d_in[8];
    const float* msg_w1   = (const float*)d_in[9];
    const float* msg_b1   = (const float*)d_in[10];
    const float* msg_w2   = (const float*)d_in[11];
    const float* msg_b2   = (const float*)d_in[12];
    const float* upd_w1   = (const float*)d_in[13];
    const float* upd_b1   = (const float*)d_in[14];
    const float* upd_w2   = (const float*)d_in[15];
    const float* upd_b2   = (const float*)d_in[16];
    const float* pre_w1   = (const float*)d_in[17];
    const float* pre_b1   = (const float*)d_in[18];
    const float* pre_w2   = (const float*)d_in[19];
    const float* pre_b2   = (const float*)d_in[20];
    const float* ro_w1    = (const float*)d_in[21];
    const float* ro_b1    = (const float*)d_in[22];
    const float* ro_w2    = (const float*)d_in[23];
    const float* ro_b2    = (const float*)d_in[24];

    const int E = in_sizes[3] / 2;
    const int N = in_sizes[4];
    const int G = out_size;

    char* ws = (char*)d_ws;
    size_t off = 0;
    auto alloc = [&](size_t bytes){ void* p = ws + off; off += (bytes + 255) & ~(size_t)255; return p; };
    short* hbf    = (short*)alloc((size_t)N*HDIM*2);
    float* aggr   = (float*)alloc((size_t)N*HDIM*4);
    float* stageA = (float*)alloc((size_t)N*HDIM*4);
    float* stageB = (float*)alloc((size_t)N*HDIM*4);
    float* pooled = (float*)alloc((size_t)G*HDIM*4);
    short* wsw    = (short*)alloc((size_t)59*3072*2);
    short* w1sr   = (short*)alloc((size_t)4*18432*2);
    short* SR     = (short*)alloc((size_t)N*192*2);
    int*   deg    = (int*)alloc((size_t)N*4);
    int*   cur    = (int*)alloc((size_t)N*4);
    int*   part   = (int*)alloc((size_t)256*4);
    int2*  sd_s   = (int2*)alloc((size_t)E*8);
    int*   rec_s  = (int*)alloc((size_t)E*4);

    hipMemsetAsync(deg, 0, (size_t)N*4, stream);   // must precede swizzle_all (hist phase)

    SwTable T;
    for (int jj=0;jj<22;jj++){ T.j[jj].src = embed_w1; T.j[jj].ck = 1<<30; T.j[jj].ks = 0; T.j[jj].ksrc = 0; }
    int ck = 0, ji = 0;
    auto add = [&](const float* s, int ks, int ksrc){
        T.j[ji].src = s; T.j[ji].ck = ck; T.j[ji].ks = ks; T.j[ji].ksrc = ksrc;
        ji++; ck += ks;
    };
    add(embed_w1, 2, 35);   // ck 0
    add(embed_w2, 3, 96);   // ck 2
    add(pre_w1,   3, 96);   // ck 5
    add(pre_w2,   3, 96);   // ck 8
    for (int l=0;l<4;l++) add(msg_w2 + (size_t)l*96*96,  3, 96);   // ck 11+3l
    for (int l=0;l<4;l++) add(upd_w1 + (size_t)l*192*96, 6, 192);  // ck 23+6l
    for (int l=0;l<4;l++) add(upd_w2 + (size_t)l*96*96,  3, 96);   // ck 47+3l
    const int total1 = 59*3072;
    const int total2 = 4*18432;
    const int nA = N*24;           // aggr float4s
    const int nP = G*24;           // pooled float4s
    const int totalAll = total1 + total2 + nA + nP + E;
    swizzle_all<<<(totalAll+255)/256, 256, 0, stream>>>(T, msg_w1, wsw, w1sr, total1, total2,
                                                       aggr, pooled, nA, nP, ei + E, deg, E);

    const int nbE256 = (E + 255) / 256;
    const int nbScan = (N + 1023) / 1024;
    scan_part<<<nbScan, 256, 0, stream>>>(deg, part, N);
    scan_top<<<1, 256, 0, stream>>>(part, nbScan);
    scan_final<<<nbScan, 256, 0, stream>>>(deg, part, cur, N);
    scatter_kernel<<<nbE256, 256, 0, stream>>>(ei, ei + E, pos, cur, sd_s, rec_s, E);

    const int nbN = (N + NTILE - 1) / NTILE;
    embed_kernel<<<nbN, 256, 0, stream>>>(x, pe, wsw + 0, embed_b1, wsw + 2*3072, embed_b2,
                                          hbf, w1sr, msg_b1, SR, N);

    const int nbE = (E + TILE - 1) / TILE;
    for (int l = 0; l < 4; ++l) {
        edge_kernel<<<nbE, 256, 0, stream>>>(SR, sd_s, rec_s,
            msg_w1 + (size_t)l*193*96 + (size_t)192*96,
            wsw + (11 + 3*l)*3072, msg_b2 + l*96, aggr, stageA, stageB, E);
        const short* w1sr_next  = (l < 3) ? (w1sr + (size_t)(l+1)*18432) : nullptr;
        const float* msgb1_next = (l < 3) ? (msg_b1 + (l+1)*96) : nullptr;
        const short* pw1 = (l == 3) ? (wsw + 5*3072) : nullptr;
        const float* pb1 = (l == 3) ? pre_b1 : nullptr;
        const short* pw2 = (l == 3) ? (wsw + 8*3072) : nullptr;
        const float* pb2 = (l == 3) ? pre_b2 : nullptr;
        update_kernel<<<nbN, 256, 0, stream>>>(hbf, aggr, stageA, stageB, deg,
            wsw + (23 + 6*l)*3072, upd_b1 + l*96,
            wsw + (47 + 3*l)*3072, upd_b2 + l*96,
            w1sr_next, msgb1_next, SR,
            pw1, pb1, pw2, pb2, batch, pooled, N);
    }

    readout_kernel<<<G, 128, 0, stream>>>(pooled, ro_w1, ro_b1, ro_w2, ro_b2, (float*)d_out);
}